// Round 1
// baseline (754.907 us; speedup 1.0000x reference)
//
#include <hip/hip_runtime.h>

typedef unsigned short u16;
typedef __attribute__((ext_vector_type(8))) __bf16 bf16x8;
typedef __attribute__((ext_vector_type(4))) float floatx4;

#define DEV static __device__ __forceinline__

DEV float lo2f(unsigned v){ return __uint_as_float(v << 16); }
DEV float hi2f(unsigned v){ return __uint_as_float(v & 0xffff0000u); }
DEV float bu2f(u16 v){ return __uint_as_float(((unsigned)v) << 16); }
DEV u16 f2b(float f){
  unsigned u = __float_as_uint(f);
  return (u16)((u + 0x7fffu + ((u >> 16) & 1u)) >> 16);
}
// fast erf-gelu: Abramowitz-Stegun 7.1.26, |err_erf| < 1.5e-7
DEV float geluf(float x){
  float u  = x * 0.70710678118654752440f;
  float au = fabsf(u);
  float t  = 1.0f / fmaf(0.3275911f, au, 1.0f);
  float p  = t*(0.254829592f + t*(-0.284496736f + t*(1.421413741f +
             t*(-1.453152027f + t*1.061405429f))));
  float e  = __expf(-au*au);
  float E  = fmaf(-p, e, 1.0f);
  float er = copysignf(E, u);
  return 0.5f * x * (1.0f + er);
}

// ---------------------------------------------------------------------------
// Weight pre-pack: f32 B (K x N row-major) -> bf16 frag layout
//   dst[((kk*N + n)*4 + q)*8 + j] = B[kk*32 + q*8 + j][n]
// ---------------------------------------------------------------------------
__global__ __launch_bounds__(256) void k_pack(
    const float* __restrict__ lw1, const float* __restrict__ lw2, const float* __restrict__ poolw,
    const float* __restrict__ mw1, const float* __restrict__ mw2, const float* __restrict__ uw1,
    const float* __restrict__ uw2, const float* __restrict__ bcw, const float* __restrict__ headw,
    u16* __restrict__ dst)
{
  int b = blockIdx.x;
  const float* src; int N, off, remap = 0;
  if      (b < 128){            src = lw1;  N=256; off = 0;      }
  else if (b < 256){ b -= 128;  src = lw2;  N=128; off = 32768;  }
  else if (b < 320){ b -= 256;  src = poolw;N=128; off = 65536;  }
  else if (b < 448){ b -= 320;  src = mw1;  N=256; off = 81920;  remap = 1; }
  else if (b < 512){ b -= 448;  src = mw2;  N=128; off = 114688; }
  else if (b < 640){ b -= 512;  src = uw1;  N=128; off = 131072; }
  else if (b < 704){ b -= 640;  src = uw2;  N=128; off = 163840; }
  else if (b < 768){ b -= 704;  src = bcw;  N=128; off = 180224; }
  else             { b -= 768;  src = headw;N=256; off = 196608; }
  int e = b * 256 + threadIdx.x;
  int j = e & 7, q = (e >> 3) & 3, rest = e >> 5;
  int n = rest % N, kk = rest / N;
  int k = kk * 32 + q * 8 + j;
  float v;
  if (remap) v = (n < 128) ? src[k * 128 + n] : src[(128 + k) * 128 + (n - 128)];
  else       v = src[k * N + n];
  dst[off + e] = f2b(v);
}

// ---------------------------------------------------------------------------
// k_local: h = emb[tok]+pos[c]; local = h + gelu(LN(h)@lw1+lb1)@lw2+lb2.
// 64 tokens/block, 4 waves. NEW: also emits per-chunk (8-token) mean of the
// f32 local values -> summ (bf16), replacing the separate pool-mean pass.
// ---------------------------------------------------------------------------
__global__ __launch_bounds__(256) void k_local(
    const int* __restrict__ x, const float* __restrict__ emb, const float* __restrict__ pos,
    const u16* __restrict__ lw1p, const float* __restrict__ lb1,
    const u16* __restrict__ lw2p, const float* __restrict__ lb2,
    const float* __restrict__ g, const float* __restrict__ bb,
    u16* __restrict__ outL, u16* __restrict__ summ)
{
  __shared__ u16 sA[64][136];     // LN'd activations bf16
  __shared__ u16 sY[64][136];     // gelu hidden bf16 (one 128-col half at a time)
  __shared__ int stok[64];
  __shared__ float ps[64][4], ps2[64][4], smu[64], srs[64];
  const int tid = threadIdx.x;
  const int m0 = blockIdx.x * 64;
  if (tid < 64) stok[tid] = x[m0 + tid];
  __syncthreads();
  const int r = tid >> 2, sg = tid & 3;
  float h[32];
  {
    const int tok = stok[r];
    const int c = (m0 + r) & 7;
    const float4* e4 = (const float4*)(emb + (size_t)tok * 128 + sg * 32);
    const float4* p4 = (const float4*)(pos + c * 128 + sg * 32);
    float s = 0.f, s2 = 0.f;
#pragma unroll
    for (int i = 0; i < 8; i++){
      float4 ev = e4[i], pv = p4[i];
      float v0 = ev.x + pv.x, v1 = ev.y + pv.y, v2 = ev.z + pv.z, v3 = ev.w + pv.w;
      h[i * 4 + 0] = v0; h[i * 4 + 1] = v1; h[i * 4 + 2] = v2; h[i * 4 + 3] = v3;
      s += v0 + v1 + v2 + v3;
      s2 += v0 * v0 + v1 * v1 + v2 * v2 + v3 * v3;
    }
    ps[r][sg] = s; ps2[r][sg] = s2;
  }
  __syncthreads();
  if (tid < 64){
    float s  = ps[tid][0] + ps[tid][1] + ps[tid][2] + ps[tid][3];
    float s2 = ps2[tid][0] + ps2[tid][1] + ps2[tid][2] + ps2[tid][3];
    float mu = s * (1.f / 128.f);
    smu[tid] = mu;
    srs[tid] = rsqrtf(s2 * (1.f / 128.f) - mu * mu + 1e-5f);
  }
  __syncthreads();
  {
    float mu = smu[r], rs = srs[r];
#pragma unroll
    for (int i = 0; i < 32; i++){
      int col = sg * 32 + i;
      sA[r][col] = f2b((h[i] - mu) * rs * g[col] + bb[col]);
    }
  }
  __syncthreads();
  const int lane = tid & 63, wv = tid >> 6, l15 = lane & 15, q = lane >> 4;
  // GEMM1 (64x128)@(128x256) and GEMM2 (64x256)@(256x128), N1/K2 split in halves
  floatx4 a2[8];
#pragma unroll
  for (int i = 0; i < 8; i++) a2[i] = (floatx4)(0.0f);
#pragma unroll
  for (int half = 0; half < 2; half++){
    floatx4 a1[8];
#pragma unroll
    for (int i = 0; i < 8; i++) a1[i] = (floatx4)(0.0f);
#pragma unroll
    for (int kk = 0; kk < 4; kk++){
      bf16x8 av = *(const bf16x8*)&sA[wv * 16 + l15][kk * 32 + q * 8];
#pragma unroll
      for (int nt = 0; nt < 8; nt++){
        bf16x8 bv = *(const bf16x8*)(lw1p + (size_t)((kk * 256 + (half * 8 + nt) * 16 + l15) * 4 + q) * 8);
        a1[nt] = __builtin_amdgcn_mfma_f32_16x16x32_bf16(av, bv, a1[nt], 0, 0, 0);
      }
    }
    __syncthreads();   // previous half's sY reads complete before overwrite
#pragma unroll
    for (int nt = 0; nt < 8; nt++){
      int col = nt * 16 + l15;
      float bval = lb1[half * 128 + col];
#pragma unroll
      for (int rr = 0; rr < 4; rr++)
        sY[wv * 16 + q * 4 + rr][col] = f2b(geluf(a1[nt][rr] + bval));
    }
    __syncthreads();   // Y-half writes visible
#pragma unroll
    for (int k = 0; k < 4; k++){
      bf16x8 yv = *(const bf16x8*)&sY[wv * 16 + l15][k * 32 + q * 8];
#pragma unroll
      for (int nt = 0; nt < 8; nt++){
        bf16x8 bv = *(const bf16x8*)(lw2p + (size_t)(((half * 4 + k) * 128 + nt * 16 + l15) * 4 + q) * 8);
        a2[nt] = __builtin_amdgcn_mfma_f32_16x16x32_bf16(yv, bv, a2[nt], 0, 0, 0);
      }
    }
  }
#pragma unroll
  for (int nt = 0; nt < 8; nt++){
    int col = nt * 16 + l15;
    float bval = lb2[col];
    float csum = 0.f;
#pragma unroll
    for (int rr = 0; rr < 4; rr++){
      int row = wv * 16 + q * 4 + rr;
      int gr = m0 + row;
      int tok = stok[row], c = gr & 7;
      float hres = emb[(size_t)tok * 128 + col] + pos[c * 128 + col];
      float v = a2[nt][rr] + bval + hres;
      outL[(size_t)gr * 128 + col] = f2b(v);
      csum += v;
    }
    // rows q*4+rr: q pairs (0,1) and (2,3) form the two chunks of this wave tile
    csum += __shfl_xor(csum, 16, 64);
    if (!(q & 1)){
      int chunk = blockIdx.x * 8 + 2 * wv + (q >> 1);
      summ[(size_t)chunk * 128 + col] = f2b(csum * 0.125f);
    }
  }
}

// ---------------------------------------------------------------------------
// Fused message-passing: pool GEMM + 3 rounds (PQ, msg, agg, t2, upd, LN)
// + bc GEMM, all in LDS. 256 blocks x 320 threads (5 waves, 16-row tiles).
// Block owns nodes [m0, m0+64); computes an 80-row panel with a 12-node
// backward halo (halo=0 at batch-row starts). Round k yields valid rows
// >= 4(k-1); after round 3 rows [halo, halo+64) are exact.
// ---------------------------------------------------------------------------
template<int NT>
DEV void mma_k128(floatx4* acc, const u16* A, int ap, const u16* Bp, int l15, int q){
  const u16* ar = A + l15 * ap + q * 8;
#pragma unroll
  for (int kk = 0; kk < 4; kk++){
    bf16x8 av = *(const bf16x8*)(ar + kk * 32);
#pragma unroll
    for (int nt = 0; nt < NT; nt++){
      bf16x8 bv = *(const bf16x8*)(Bp + (size_t)((kk * NT * 16 + nt * 16 + l15) * 4 + q) * 8);
      acc[nt] = __builtin_amdgcn_mfma_f32_16x16x32_bf16(av, bv, acc[nt], 0, 0, 0);
    }
  }
}

template<int NT, bool GELU>
DEV void store_lds(const floatx4* acc, const float* bias, u16* C, int cp, int l15, int q){
#pragma unroll
  for (int nt = 0; nt < NT; nt++){
    int col = nt * 16 + l15;
    float bval = bias ? bias[col] : 0.f;
#pragma unroll
    for (int rr = 0; rr < 4; rr++){
      float v = acc[nt][rr] + bval;
      if (GELU) v = geluf(v);
      C[(q * 4 + rr) * cp + col] = f2b(v);
    }
  }
}

__global__ __launch_bounds__(320) void k_rounds(
    const u16* __restrict__ summB,
    const u16* __restrict__ poolp, const float* __restrict__ poolb,
    const u16* __restrict__ mw1p, const float* __restrict__ mb1,
    const u16* __restrict__ mw2p, const float* __restrict__ mb2,
    const u16* __restrict__ uw1p, const float* __restrict__ ub1,
    const u16* __restrict__ uw2p, const float* __restrict__ ub2,
    const float* __restrict__ mlng, const float* __restrict__ mlnb,
    const u16* __restrict__ bcp, const float* __restrict__ bcb,
    u16* __restrict__ bcB)
{
  __shared__ u16 sH[80][136];   // hmsg
  __shared__ u16 sPQ[80][264];  // [P|Q]; reused: agg in [0:128], upd in [128:256]
  __shared__ u16 sS[80][136];   // msg means; reused for t2
  const int tid = threadIdx.x;
  const int m0 = blockIdx.x * 64;
  const int halo = (m0 & 1023) ? 12 : 0;
  const int lo = m0 - halo;
  // stage summ rows lo..lo+79 (clamped) into sS
  {
    int rr = tid >> 2, sg = tid & 3;
    int node = lo + rr; if (node > 16383) node = 16383;
    const uint4* src = (const uint4*)(summB + (size_t)node * 128 + sg * 32);
    uint4* dst = (uint4*)&sS[rr][sg * 32];
#pragma unroll
    for (int i = 0; i < 4; i++) dst[i] = src[i];
  }
  __syncthreads();
  const int lane = tid & 63, wv = tid >> 6, l15 = lane & 15, q = lane >> 4;
  const int d0 = lane * 2;
  const float b1lo = mb1[d0],  b1hi = mb1[d0 + 1];
  const float glo  = mlng[d0], ghi  = mlng[d0 + 1];
  const float blo  = mlnb[d0], bhi  = mlnb[d0 + 1];
  // hmsg = summ @ pool_w + pool_b
  {
    floatx4 acc[8];
#pragma unroll
    for (int i = 0; i < 8; i++) acc[i] = (floatx4)(0.0f);
    mma_k128<8>(acc, &sS[wv * 16][0], 136, poolp, l15, q);
    store_lds<8, false>(acc, poolb, &sH[wv * 16][0], 136, l15, q);
  }
  __syncthreads();
  for (int rnd = 0; rnd < 3; rnd++){
    { // [P|Q] = hmsg @ mw1
      floatx4 acc[16];
#pragma unroll
      for (int i = 0; i < 16; i++) acc[i] = (floatx4)(0.0f);
      mma_k128<16>(acc, &sH[wv * 16][0], 136, mw1p, l15, q);
      store_lds<16, false>(acc, nullptr, &sPQ[wv * 16][0], 264, l15, q);
    }
    __syncthreads();
    { // msg: s[r] = mean_d gelu(P[r] + Q[r-d] + b1)
      for (int it = 0; it < 16; it++){
        int rr = wv * 16 + it;
        int i = (lo + rr) & 1023;
        int nd = (i + 1 < 5) ? i + 1 : 5;
        int ndc = (nd < rr + 1) ? nd : rr + 1;   // clamp for garbage halo rows
        unsigned pv = *(const unsigned*)&sPQ[rr][d0];
        float p0 = lo2f(pv) + b1lo, p1 = hi2f(pv) + b1hi;
        float a0 = 0.f, a1 = 0.f;
        for (int d = 0; d < ndc; d++){
          unsigned qv = *(const unsigned*)&sPQ[rr - d][128 + d0];
          a0 += geluf(p0 + lo2f(qv));
          a1 += geluf(p1 + hi2f(qv));
        }
        float inv = 1.f / (float)nd;
        unsigned pack = (unsigned)f2b(a0 * inv) | (((unsigned)f2b(a1 * inv)) << 16);
        *(unsigned*)&sS[rr][d0] = pack;
      }
    }
    __syncthreads();
    { // agg = s @ mw2 + mb2 -> sPQ[:,0:128]
      floatx4 acc[8];
#pragma unroll
      for (int i = 0; i < 8; i++) acc[i] = (floatx4)(0.0f);
      mma_k128<8>(acc, &sS[wv * 16][0], 136, mw2p, l15, q);
      store_lds<8, false>(acc, mb2, &sPQ[wv * 16][0], 264, l15, q);
    }
    __syncthreads();
    { // t2 = gelu(hmsg @ uw1[0:128] + agg @ uw1[128:256] + ub1) -> sS
      floatx4 acc[8];
#pragma unroll
      for (int i = 0; i < 8; i++) acc[i] = (floatx4)(0.0f);
      mma_k128<8>(acc, &sH[wv * 16][0], 136, uw1p, l15, q);
      mma_k128<8>(acc, &sPQ[wv * 16][0], 264, uw1p + 16384, l15, q);
      store_lds<8, true>(acc, ub1, &sS[wv * 16][0], 136, l15, q);
    }
    __syncthreads();
    { // upd = t2 @ uw2 + ub2 -> sPQ[:,128:256]
      floatx4 acc[8];
#pragma unroll
      for (int i = 0; i < 8; i++) acc[i] = (floatx4)(0.0f);
      mma_k128<8>(acc, &sS[wv * 16][0], 136, uw2p, l15, q);
      store_lds<8, false>(acc, ub2, &sPQ[wv * 16][128], 264, l15, q);
    }
    __syncthreads();
    { // hmsg = LN(hmsg + upd) in place
      for (int it = 0; it < 16; it++){
        int rr = wv * 16 + it;
        unsigned hv = *(const unsigned*)&sH[rr][d0];
        unsigned uv = *(const unsigned*)&sPQ[rr][128 + d0];
        float x0 = lo2f(hv) + lo2f(uv);
        float x1 = hi2f(hv) + hi2f(uv);
        float s = x0 + x1, s2 = x0 * x0 + x1 * x1;
#pragma unroll
        for (int off = 32; off; off >>= 1){
          s  += __shfl_xor(s, off, 64);
          s2 += __shfl_xor(s2, off, 64);
        }
        float mu = s * (1.f / 128.f);
        float rs = rsqrtf(s2 * (1.f / 128.f) - mu * mu + 1e-5f);
        float y0 = (x0 - mu) * rs * glo + blo;
        float y1 = (x1 - mu) * rs * ghi + bhi;
        unsigned pack = (unsigned)f2b(y0) | (((unsigned)f2b(y1)) << 16);
        *(unsigned*)&sH[rr][d0] = pack;
      }
    }
    __syncthreads();
  }
  { // bc = hmsg @ bc_w + bc_b, write owned rows only
    floatx4 acc[8];
#pragma unroll
    for (int i = 0; i < 8; i++) acc[i] = (floatx4)(0.0f);
    mma_k128<8>(acc, &sH[wv * 16][0], 136, bcp, l15, q);
#pragma unroll
    for (int nt = 0; nt < 8; nt++){
      int col = nt * 16 + l15;
      float bval = bcb[col];
#pragma unroll
      for (int rr = 0; rr < 4; rr++){
        int row = wv * 16 + q * 4 + rr;
        if (row >= halo && row < halo + 64){
          int node = lo + row;
          bcB[(size_t)node * 128 + col] = f2b(acc[nt][rr] + bval);
        }
      }
    }
  }
}

// ---------------------------------------------------------------------------
// k_head: out = LN(local + bc[chunk]) @ head_w  (131072 x 128 x 256), f32 out
// ---------------------------------------------------------------------------
__global__ __launch_bounds__(256) void k_head(
    const u16* __restrict__ localL, const u16* __restrict__ bcB,
    const float* __restrict__ g, const float* __restrict__ bb,
    const u16* __restrict__ headp, float* __restrict__ out)
{
  __shared__ u16 sA[64][136];
  __shared__ float ps[64][4], ps2[64][4], smu[64], srs[64];
  const int tid = threadIdx.x;
  const int m0 = blockIdx.x * 64;
  const int r = tid >> 2, sg = tid & 3;
  float h[32];
  {
    const int gr = m0 + r;
    const int ch = gr >> 3;
    const uint4* l4 = (const uint4*)(localL + (size_t)gr * 128 + sg * 32);
    const uint4* c4 = (const uint4*)(bcB + (size_t)ch * 128 + sg * 32);
    float s = 0.f, s2 = 0.f;
#pragma unroll
    for (int i = 0; i < 4; i++){
      uint4 lv = l4[i], cv = c4[i];
      unsigned lw[4] = {lv.x, lv.y, lv.z, lv.w}, cw[4] = {cv.x, cv.y, cv.z, cv.w};
#pragma unroll
      for (int j = 0; j < 4; j++){
        float v0 = lo2f(lw[j]) + lo2f(cw[j]);
        float v1 = hi2f(lw[j]) + hi2f(cw[j]);
        h[i * 8 + j * 2] = v0; h[i * 8 + j * 2 + 1] = v1;
        s += v0 + v1; s2 += v0 * v0 + v1 * v1;
      }
    }
    ps[r][sg] = s; ps2[r][sg] = s2;
  }
  __syncthreads();
  if (tid < 64){
    float s  = ps[tid][0] + ps[tid][1] + ps[tid][2] + ps[tid][3];
    float s2 = ps2[tid][0] + ps2[tid][1] + ps2[tid][2] + ps2[tid][3];
    float mu = s * (1.f / 128.f);
    smu[tid] = mu;
    srs[tid] = rsqrtf(s2 * (1.f / 128.f) - mu * mu + 1e-5f);
  }
  __syncthreads();
  {
    float mu = smu[r], rs = srs[r];
#pragma unroll
    for (int i = 0; i < 32; i++){
      int col = sg * 32 + i;
      sA[r][col] = f2b((h[i] - mu) * rs * g[col] + bb[col]);
    }
  }
  __syncthreads();
  const int lane = tid & 63, wv = tid >> 6, l15 = lane & 15, q = lane >> 4;
  floatx4 acc[16];
#pragma unroll
  for (int i = 0; i < 16; i++) acc[i] = (floatx4)(0.0f);
#pragma unroll
  for (int kk = 0; kk < 4; kk++){
    bf16x8 av = *(const bf16x8*)&sA[wv * 16 + l15][kk * 32 + q * 8];
#pragma unroll
    for (int nt = 0; nt < 16; nt++){
      bf16x8 bv = *(const bf16x8*)(headp + (size_t)((kk * 256 + nt * 16 + l15) * 4 + q) * 8);
      acc[nt] = __builtin_amdgcn_mfma_f32_16x16x32_bf16(av, bv, acc[nt], 0, 0, 0);
    }
  }
#pragma unroll
  for (int nt = 0; nt < 16; nt++){
    int col = nt * 16 + l15;
#pragma unroll
    for (int rr = 0; rr < 4; rr++){
      int row = wv * 16 + q * 4 + rr;
      out[(size_t)(m0 + row) * 256 + col] = acc[nt][rr];
    }
  }
}

// ---------------------------------------------------------------------------

extern "C" void kernel_launch(void* const* d_in, const int* in_sizes, int n_in,
                              void* d_out, int out_size, void* d_ws, size_t ws_size,
                              hipStream_t stream)
{
  const int*   x     = (const int*)d_in[0];
  const float* emb   = (const float*)d_in[1];
  const float* pos   = (const float*)d_in[2];
  const float* lw1   = (const float*)d_in[3];
  const float* lb1   = (const float*)d_in[4];
  const float* lw2   = (const float*)d_in[5];
  const float* lb2   = (const float*)d_in[6];
  const float* llng  = (const float*)d_in[7];
  const float* llnb  = (const float*)d_in[8];
  const float* poolw = (const float*)d_in[9];
  const float* poolb = (const float*)d_in[10];
  const float* mw1   = (const float*)d_in[11];
  const float* mb1   = (const float*)d_in[12];
  const float* mw2   = (const float*)d_in[13];
  const float* mb2   = (const float*)d_in[14];
  const float* uw1   = (const float*)d_in[15];
  const float* ub1   = (const float*)d_in[16];
  const float* uw2   = (const float*)d_in[17];
  const float* ub2   = (const float*)d_in[18];
  const float* mlng  = (const float*)d_in[19];
  const float* mlnb  = (const float*)d_in[20];
  const float* bcw   = (const float*)d_in[21];
  const float* bcb   = (const float*)d_in[22];
  const float* flng  = (const float*)d_in[23];
  const float* flnb  = (const float*)d_in[24];
  const float* headw = (const float*)d_in[25];

  // ws layout (~38.3 MB): packed weights | localB bf16 | bcB bf16
  char* ws = (char*)d_ws;
  u16* wpack = (u16*)ws;
  u16* lw1p  = wpack;
  u16* lw2p  = wpack + 32768;
  u16* poolp = wpack + 65536;
  u16* mw1p  = wpack + 81920;
  u16* mw2p  = wpack + 114688;
  u16* uw1p  = wpack + 131072;
  u16* uw2p  = wpack + 163840;
  u16* bcp   = wpack + 180224;
  u16* headp = wpack + 196608;
  u16* localB = (u16*)(ws + 524288);       // 131072 x 128 bf16 = 33.55 MB
  u16* bcB    = (u16*)(ws + 34078720);     // 16384 x 128 bf16  = 4.19 MB

  // chunk means live in d_out (dead before k_head, which overwrites all of it)
  u16* summB = (u16*)d_out;                // 16384 x 128 bf16 = 4.19 MB

  k_pack<<<896, 256, 0, stream>>>(lw1, lw2, poolw, mw1, mw2, uw1, uw2, bcw, headw, wpack);
  k_local<<<2048, 256, 0, stream>>>(x, emb, pos, lw1p, lb1, lw2p, lb2, llng, llnb, localB, summB);
  k_rounds<<<256, 320, 0, stream>>>(summB, poolp, poolb, mw1p, mb1, mw2p, mb2,
                                    uw1p, ub1, uw2p, ub2, mlng, mlnb, bcp, bcb, bcB);
  k_head<<<2048, 256, 0, stream>>>(localB, bcB, flng, flnb, headp, (float*)d_out);
}

// Round 2
// 480.110 us; speedup vs baseline: 1.5724x; 1.5724x over previous
//
#include <hip/hip_runtime.h>

typedef unsigned short u16;
typedef __attribute__((ext_vector_type(8))) __bf16 bf16x8;
typedef __attribute__((ext_vector_type(4))) float floatx4;

#define DEV static __device__ __forceinline__

DEV float lo2f(unsigned v){ return __uint_as_float(v << 16); }
DEV float hi2f(unsigned v){ return __uint_as_float(v & 0xffff0000u); }
DEV float bu2f(u16 v){ return __uint_as_float(((unsigned)v) << 16); }
DEV u16 f2b(float f){
  unsigned u = __float_as_uint(f);
  return (u16)((u + 0x7fffu + ((u >> 16) & 1u)) >> 16);
}
// fast erf-gelu: Abramowitz-Stegun 7.1.26, |err_erf| < 1.5e-7
DEV float geluf(float x){
  float u  = x * 0.70710678118654752440f;
  float au = fabsf(u);
  float t  = 1.0f / fmaf(0.3275911f, au, 1.0f);
  float p  = t*(0.254829592f + t*(-0.284496736f + t*(1.421413741f +
             t*(-1.453152027f + t*1.061405429f))));
  float e  = __expf(-au*au);
  float E  = fmaf(-p, e, 1.0f);
  float er = copysignf(E, u);
  return 0.5f * x * (1.0f + er);
}

// ---------------------------------------------------------------------------
// Weight pre-pack: f32 B (K x N row-major) -> bf16 frag layout
//   dst[((kk*N + n)*4 + q)*8 + j] = B[kk*32 + q*8 + j][n]
// mw1 is packed as TWO contiguous N=128 panels (P rows 0:128, Q rows 128:256)
// so each panel is one 32 KB contiguous block for LDS staging.
// ---------------------------------------------------------------------------
__global__ __launch_bounds__(256) void k_pack(
    const float* __restrict__ lw1, const float* __restrict__ lw2, const float* __restrict__ poolw,
    const float* __restrict__ mw1, const float* __restrict__ mw2, const float* __restrict__ uw1,
    const float* __restrict__ uw2, const float* __restrict__ bcw, const float* __restrict__ headw,
    u16* __restrict__ dst)
{
  int b = blockIdx.x;
  const float* src; int N, off;
  if      (b < 128){            src = lw1;  N=256; off = 0;      }
  else if (b < 256){ b -= 128;  src = lw2;  N=128; off = 32768;  }
  else if (b < 320){ b -= 256;  src = poolw;N=128; off = 65536;  }
  else if (b < 384){ b -= 320;  src = mw1;  N=128; off = 81920;  }          // mw1 P half
  else if (b < 448){ b -= 384;  src = mw1 + 16384; N=128; off = 98304; }    // mw1 Q half
  else if (b < 512){ b -= 448;  src = mw2;  N=128; off = 114688; }
  else if (b < 640){ b -= 512;  src = uw1;  N=128; off = 131072; }
  else if (b < 704){ b -= 640;  src = uw2;  N=128; off = 163840; }
  else if (b < 768){ b -= 704;  src = bcw;  N=128; off = 180224; }
  else             { b -= 768;  src = headw;N=256; off = 196608; }
  int e = b * 256 + threadIdx.x;
  int j = e & 7, q = (e >> 3) & 3, rest = e >> 5;
  int n = rest % N, kk = rest / N;
  int k = kk * 32 + q * 8 + j;
  dst[off + e] = f2b(src[k * N + n]);
}

// ---------------------------------------------------------------------------
// k_local: h = emb[tok]+pos[c]; local = h + gelu(LN(h)@lw1+lb1)@lw2+lb2.
// 64 tokens/block, 4 waves. Also emits per-chunk (8-token) mean of the
// f32 local values -> summ (bf16).
// ---------------------------------------------------------------------------
__global__ __launch_bounds__(256) void k_local(
    const int* __restrict__ x, const float* __restrict__ emb, const float* __restrict__ pos,
    const u16* __restrict__ lw1p, const float* __restrict__ lb1,
    const u16* __restrict__ lw2p, const float* __restrict__ lb2,
    const float* __restrict__ g, const float* __restrict__ bb,
    u16* __restrict__ outL, u16* __restrict__ summ)
{
  __shared__ u16 sA[64][136];     // LN'd activations bf16
  __shared__ u16 sY[64][136];     // gelu hidden bf16 (one 128-col half at a time)
  __shared__ int stok[64];
  __shared__ float ps[64][4], ps2[64][4], smu[64], srs[64];
  const int tid = threadIdx.x;
  const int m0 = blockIdx.x * 64;
  if (tid < 64) stok[tid] = x[m0 + tid];
  __syncthreads();
  const int r = tid >> 2, sg = tid & 3;
  float h[32];
  {
    const int tok = stok[r];
    const int c = (m0 + r) & 7;
    const float4* e4 = (const float4*)(emb + (size_t)tok * 128 + sg * 32);
    const float4* p4 = (const float4*)(pos + c * 128 + sg * 32);
    float s = 0.f, s2 = 0.f;
#pragma unroll
    for (int i = 0; i < 8; i++){
      float4 ev = e4[i], pv = p4[i];
      float v0 = ev.x + pv.x, v1 = ev.y + pv.y, v2 = ev.z + pv.z, v3 = ev.w + pv.w;
      h[i * 4 + 0] = v0; h[i * 4 + 1] = v1; h[i * 4 + 2] = v2; h[i * 4 + 3] = v3;
      s += v0 + v1 + v2 + v3;
      s2 += v0 * v0 + v1 * v1 + v2 * v2 + v3 * v3;
    }
    ps[r][sg] = s; ps2[r][sg] = s2;
  }
  __syncthreads();
  if (tid < 64){
    float s  = ps[tid][0] + ps[tid][1] + ps[tid][2] + ps[tid][3];
    float s2 = ps2[tid][0] + ps2[tid][1] + ps2[tid][2] + ps2[tid][3];
    float mu = s * (1.f / 128.f);
    smu[tid] = mu;
    srs[tid] = rsqrtf(s2 * (1.f / 128.f) - mu * mu + 1e-5f);
  }
  __syncthreads();
  {
    float mu = smu[r], rs = srs[r];
#pragma unroll
    for (int i = 0; i < 32; i++){
      int col = sg * 32 + i;
      sA[r][col] = f2b((h[i] - mu) * rs * g[col] + bb[col]);
    }
  }
  __syncthreads();
  const int lane = tid & 63, wv = tid >> 6, l15 = lane & 15, q = lane >> 4;
  // GEMM1 (64x128)@(128x256) and GEMM2 (64x256)@(256x128), N1/K2 split in halves
  floatx4 a2[8];
#pragma unroll
  for (int i = 0; i < 8; i++) a2[i] = (floatx4)(0.0f);
#pragma unroll
  for (int half = 0; half < 2; half++){
    floatx4 a1[8];
#pragma unroll
    for (int i = 0; i < 8; i++) a1[i] = (floatx4)(0.0f);
#pragma unroll
    for (int kk = 0; kk < 4; kk++){
      bf16x8 av = *(const bf16x8*)&sA[wv * 16 + l15][kk * 32 + q * 8];
#pragma unroll
      for (int nt = 0; nt < 8; nt++){
        bf16x8 bv = *(const bf16x8*)(lw1p + (size_t)((kk * 256 + (half * 8 + nt) * 16 + l15) * 4 + q) * 8);
        a1[nt] = __builtin_amdgcn_mfma_f32_16x16x32_bf16(av, bv, a1[nt], 0, 0, 0);
      }
    }
    __syncthreads();   // previous half's sY reads complete before overwrite
#pragma unroll
    for (int nt = 0; nt < 8; nt++){
      int col = nt * 16 + l15;
      float bval = lb1[half * 128 + col];
#pragma unroll
      for (int rr = 0; rr < 4; rr++)
        sY[wv * 16 + q * 4 + rr][col] = f2b(geluf(a1[nt][rr] + bval));
    }
    __syncthreads();   // Y-half writes visible
#pragma unroll
    for (int k = 0; k < 4; k++){
      bf16x8 yv = *(const bf16x8*)&sY[wv * 16 + l15][k * 32 + q * 8];
#pragma unroll
      for (int nt = 0; nt < 8; nt++){
        bf16x8 bv = *(const bf16x8*)(lw2p + (size_t)(((half * 4 + k) * 128 + nt * 16 + l15) * 4 + q) * 8);
        a2[nt] = __builtin_amdgcn_mfma_f32_16x16x32_bf16(yv, bv, a2[nt], 0, 0, 0);
      }
    }
  }
#pragma unroll
  for (int nt = 0; nt < 8; nt++){
    int col = nt * 16 + l15;
    float bval = lb2[col];
    float csum = 0.f;
#pragma unroll
    for (int rr = 0; rr < 4; rr++){
      int row = wv * 16 + q * 4 + rr;
      int gr = m0 + row;
      int tok = stok[row], c = gr & 7;
      float hres = emb[(size_t)tok * 128 + col] + pos[c * 128 + col];
      float v = a2[nt][rr] + bval + hres;
      outL[(size_t)gr * 128 + col] = f2b(v);
      csum += v;
    }
    // rows q*4+rr: q pairs (0,1) and (2,3) form the two chunks of this wave tile
    csum += __shfl_xor(csum, 16, 64);
    if (!(q & 1)){
      int chunk = blockIdx.x * 8 + 2 * wv + (q >> 1);
      summ[(size_t)chunk * 128 + col] = f2b(csum * 0.125f);
    }
  }
}

// ---------------------------------------------------------------------------
// Fused message-passing: pool GEMM + 3 rounds (PQ, msg, agg, t2, upd, LN)
// + bc GEMM, all in LDS. 256 blocks x 320 threads (5 waves, 16-row tiles).
// Block owns nodes [m0, m0+64); computes an 80-row panel with a 12-node
// backward halo (halo=0 at batch-row starts). Round k yields valid rows
// >= 4k; after round 3 rows [halo, halo+64) are exact.
// R2: all weight panels staged to LDS (32 KB each) once per block; all
// GEMMs are NT=8 (acc[8] = 32 VGPRs peak) to kill the R1 scratch spills.
// ---------------------------------------------------------------------------
DEV void stage32(const u16* __restrict__ g, u16* __restrict__ s, int tid){
  // copy one 32 KB panel (2048 x 16B) global -> LDS with 320 threads
  const uint4* gs = (const uint4*)g;
  uint4* ss = (uint4*)s;
#pragma unroll
  for (int k = 0; k < 6; k++) ss[tid + k * 320] = gs[tid + k * 320];
  int c = tid + 1920;
  if (c < 2048) ss[c] = gs[c];   // waves 0,1 only (uniform per wave)
}

template<int NT>
DEV void mma_k128(floatx4* acc, const u16* A, int ap, const u16* Bp, int l15, int q){
  const u16* ar = A + l15 * ap + q * 8;
#pragma unroll
  for (int kk = 0; kk < 4; kk++){
    bf16x8 av = *(const bf16x8*)(ar + kk * 32);
#pragma unroll
    for (int nt = 0; nt < NT; nt++){
      bf16x8 bv = *(const bf16x8*)(Bp + (size_t)((kk * NT * 16 + nt * 16 + l15) * 4 + q) * 8);
      acc[nt] = __builtin_amdgcn_mfma_f32_16x16x32_bf16(av, bv, acc[nt], 0, 0, 0);
    }
  }
}

template<int NT, bool GELU>
DEV void store_lds(const floatx4* acc, const float* bias, u16* C, int cp, int l15, int q){
#pragma unroll
  for (int nt = 0; nt < NT; nt++){
    int col = nt * 16 + l15;
    float bval = bias ? bias[col] : 0.f;
#pragma unroll
    for (int rr = 0; rr < 4; rr++){
      float v = acc[nt][rr] + bval;
      if (GELU) v = geluf(v);
      C[(q * 4 + rr) * cp + col] = f2b(v);
    }
  }
}

__global__ __launch_bounds__(320, 2) void k_rounds(
    const u16* __restrict__ summB,
    const u16* __restrict__ poolp, const float* __restrict__ poolb,
    const u16* __restrict__ mw1p, const float* __restrict__ mb1,
    const u16* __restrict__ mw2p, const float* __restrict__ mb2,
    const u16* __restrict__ uw1p, const float* __restrict__ ub1,
    const u16* __restrict__ uw2p, const float* __restrict__ ub2,
    const float* __restrict__ mlng, const float* __restrict__ mlnb,
    const u16* __restrict__ bcp, const float* __restrict__ bcb,
    u16* __restrict__ bcB)
{
  __shared__ __align__(16) u16 sH[80][136];   // hmsg
  __shared__ __align__(16) u16 sPQ[80][264];  // [P|Q]; reused: agg in [0:128], upd in [128:256]
  __shared__ __align__(16) u16 sS[80][136];   // summ; msg means; t2
  __shared__ __align__(16) u16 sW[16384];     // staged 32 KB weight panel
  const int tid = threadIdx.x;
  const int m0 = blockIdx.x * 64;
  const int halo = (m0 & 1023) ? 12 : 0;
  const int lo = m0 - halo;
  // stage summ rows lo..lo+79 (clamped) into sS
  {
    int rr = tid >> 2, sg = tid & 3;
    int node = lo + rr; if (node > 16383) node = 16383;
    const uint4* src = (const uint4*)(summB + (size_t)node * 128 + sg * 32);
    uint4* dst = (uint4*)&sS[rr][sg * 32];
#pragma unroll
    for (int i = 0; i < 4; i++) dst[i] = src[i];
  }
  stage32(poolp, sW, tid);
  __syncthreads();
  const int lane = tid & 63, wv = tid >> 6, l15 = lane & 15, q = lane >> 4;
  const int d0 = lane * 2;
  const float b1lo = mb1[d0],  b1hi = mb1[d0 + 1];
  const float glo  = mlng[d0], ghi  = mlng[d0 + 1];
  const float blo  = mlnb[d0], bhi  = mlnb[d0 + 1];
  // hmsg = summ @ pool_w + pool_b
  {
    floatx4 acc[8];
#pragma unroll
    for (int i = 0; i < 8; i++) acc[i] = (floatx4)(0.0f);
    mma_k128<8>(acc, &sS[wv * 16][0], 136, sW, l15, q);
    store_lds<8, false>(acc, poolb, &sH[wv * 16][0], 136, l15, q);
  }
  __syncthreads();
  for (int rnd = 0; rnd < 3; rnd++){
    stage32(mw1p, sW, tid);             // P panel (w1 rows 0:128)
    __syncthreads();
    { // P = hmsg @ w1[0:128]
      floatx4 acc[8];
#pragma unroll
      for (int i = 0; i < 8; i++) acc[i] = (floatx4)(0.0f);
      mma_k128<8>(acc, &sH[wv * 16][0], 136, sW, l15, q);
      store_lds<8, false>(acc, nullptr, &sPQ[wv * 16][0], 264, l15, q);
    }
    __syncthreads();
    stage32(mw1p + 16384, sW, tid);     // Q panel (w1 rows 128:256)
    __syncthreads();
    { // Q = hmsg @ w1[128:256]
      floatx4 acc[8];
#pragma unroll
      for (int i = 0; i < 8; i++) acc[i] = (floatx4)(0.0f);
      mma_k128<8>(acc, &sH[wv * 16][0], 136, sW, l15, q);
      store_lds<8, false>(acc, nullptr, &sPQ[wv * 16][128], 264, l15, q);
    }
    __syncthreads();
    { // msg: s[r] = mean_d gelu(P[r] + Q[r-d] + b1)
      for (int it = 0; it < 16; it++){
        int rr = wv * 16 + it;
        int i = (lo + rr) & 1023;
        int nd = (i + 1 < 5) ? i + 1 : 5;
        int ndc = (nd < rr + 1) ? nd : rr + 1;   // clamp for garbage halo rows
        unsigned pv = *(const unsigned*)&sPQ[rr][d0];
        float p0 = lo2f(pv) + b1lo, p1 = hi2f(pv) + b1hi;
        float a0 = 0.f, a1 = 0.f;
        for (int d = 0; d < ndc; d++){
          unsigned qv = *(const unsigned*)&sPQ[rr - d][128 + d0];
          a0 += geluf(p0 + lo2f(qv));
          a1 += geluf(p1 + hi2f(qv));
        }
        float inv = 1.f / (float)nd;
        unsigned pack = (unsigned)f2b(a0 * inv) | (((unsigned)f2b(a1 * inv)) << 16);
        *(unsigned*)&sS[rr][d0] = pack;
      }
    }
    __syncthreads();
    stage32(mw2p, sW, tid);
    __syncthreads();
    { // agg = s @ mw2 + mb2 -> sPQ[:,0:128]
      floatx4 acc[8];
#pragma unroll
      for (int i = 0; i < 8; i++) acc[i] = (floatx4)(0.0f);
      mma_k128<8>(acc, &sS[wv * 16][0], 136, sW, l15, q);
      store_lds<8, false>(acc, mb2, &sPQ[wv * 16][0], 264, l15, q);
    }
    __syncthreads();
    stage32(uw1p, sW, tid);             // uw1 rows 0:128
    __syncthreads();
    { // t2 = gelu(hmsg @ uw1[0:128] + agg @ uw1[128:256] + ub1) -> sS
      floatx4 acc[8];
#pragma unroll
      for (int i = 0; i < 8; i++) acc[i] = (floatx4)(0.0f);
      mma_k128<8>(acc, &sH[wv * 16][0], 136, sW, l15, q);
      __syncthreads();                  // sW reads done
      stage32(uw1p + 16384, sW, tid);   // uw1 rows 128:256
      __syncthreads();
      mma_k128<8>(acc, &sPQ[wv * 16][0], 264, sW, l15, q);
      store_lds<8, true>(acc, ub1, &sS[wv * 16][0], 136, l15, q);
    }
    __syncthreads();
    stage32(uw2p, sW, tid);
    __syncthreads();
    { // upd = t2 @ uw2 + ub2 -> sPQ[:,128:256]
      floatx4 acc[8];
#pragma unroll
      for (int i = 0; i < 8; i++) acc[i] = (floatx4)(0.0f);
      mma_k128<8>(acc, &sS[wv * 16][0], 136, sW, l15, q);
      store_lds<8, false>(acc, ub2, &sPQ[wv * 16][128], 264, l15, q);
    }
    __syncthreads();
    { // hmsg = LN(hmsg + upd) in place
      for (int it = 0; it < 16; it++){
        int rr = wv * 16 + it;
        unsigned hv = *(const unsigned*)&sH[rr][d0];
        unsigned uv = *(const unsigned*)&sPQ[rr][128 + d0];
        float x0 = lo2f(hv) + lo2f(uv);
        float x1 = hi2f(hv) + hi2f(uv);
        float s = x0 + x1, s2 = x0 * x0 + x1 * x1;
#pragma unroll
        for (int off = 32; off; off >>= 1){
          s  += __shfl_xor(s, off, 64);
          s2 += __shfl_xor(s2, off, 64);
        }
        float mu = s * (1.f / 128.f);
        float rs = rsqrtf(s2 * (1.f / 128.f) - mu * mu + 1e-5f);
        float y0 = (x0 - mu) * rs * glo + blo;
        float y1 = (x1 - mu) * rs * ghi + bhi;
        unsigned pack = (unsigned)f2b(y0) | (((unsigned)f2b(y1)) << 16);
        *(unsigned*)&sH[rr][d0] = pack;
      }
    }
    __syncthreads();
  }
  stage32(bcp, sW, tid);
  __syncthreads();
  { // bc = hmsg @ bc_w + bc_b, write owned rows only
    floatx4 acc[8];
#pragma unroll
    for (int i = 0; i < 8; i++) acc[i] = (floatx4)(0.0f);
    mma_k128<8>(acc, &sH[wv * 16][0], 136, sW, l15, q);
#pragma unroll
    for (int nt = 0; nt < 8; nt++){
      int col = nt * 16 + l15;
      float bval = bcb[col];
#pragma unroll
      for (int rr = 0; rr < 4; rr++){
        int row = wv * 16 + q * 4 + rr;
        if (row >= halo && row < halo + 64){
          int node = lo + row;
          bcB[(size_t)node * 128 + col] = f2b(acc[nt][rr] + bval);
        }
      }
    }
  }
}

// ---------------------------------------------------------------------------
// k_head: out = LN(local + bc[chunk]) @ head_w  (131072 x 128 x 256), f32 out
// ---------------------------------------------------------------------------
__global__ __launch_bounds__(256) void k_head(
    const u16* __restrict__ localL, const u16* __restrict__ bcB,
    const float* __restrict__ g, const float* __restrict__ bb,
    const u16* __restrict__ headp, float* __restrict__ out)
{
  __shared__ u16 sA[64][136];
  __shared__ float ps[64][4], ps2[64][4], smu[64], srs[64];
  const int tid = threadIdx.x;
  const int m0 = blockIdx.x * 64;
  const int r = tid >> 2, sg = tid & 3;
  float h[32];
  {
    const int gr = m0 + r;
    const int ch = gr >> 3;
    const uint4* l4 = (const uint4*)(localL + (size_t)gr * 128 + sg * 32);
    const uint4* c4 = (const uint4*)(bcB + (size_t)ch * 128 + sg * 32);
    float s = 0.f, s2 = 0.f;
#pragma unroll
    for (int i = 0; i < 4; i++){
      uint4 lv = l4[i], cv = c4[i];
      unsigned lw[4] = {lv.x, lv.y, lv.z, lv.w}, cw[4] = {cv.x, cv.y, cv.z, cv.w};
#pragma unroll
      for (int j = 0; j < 4; j++){
        float v0 = lo2f(lw[j]) + lo2f(cw[j]);
        float v1 = hi2f(lw[j]) + hi2f(cw[j]);
        h[i * 8 + j * 2] = v0; h[i * 8 + j * 2 + 1] = v1;
        s += v0 + v1; s2 += v0 * v0 + v1 * v1;
      }
    }
    ps[r][sg] = s; ps2[r][sg] = s2;
  }
  __syncthreads();
  if (tid < 64){
    float s  = ps[tid][0] + ps[tid][1] + ps[tid][2] + ps[tid][3];
    float s2 = ps2[tid][0] + ps2[tid][1] + ps2[tid][2] + ps2[tid][3];
    float mu = s * (1.f / 128.f);
    smu[tid] = mu;
    srs[tid] = rsqrtf(s2 * (1.f / 128.f) - mu * mu + 1e-5f);
  }
  __syncthreads();
  {
    float mu = smu[r], rs = srs[r];
#pragma unroll
    for (int i = 0; i < 32; i++){
      int col = sg * 32 + i;
      sA[r][col] = f2b((h[i] - mu) * rs * g[col] + bb[col]);
    }
  }
  __syncthreads();
  const int lane = tid & 63, wv = tid >> 6, l15 = lane & 15, q = lane >> 4;
  floatx4 acc[16];
#pragma unroll
  for (int i = 0; i < 16; i++) acc[i] = (floatx4)(0.0f);
#pragma unroll
  for (int kk = 0; kk < 4; kk++){
    bf16x8 av = *(const bf16x8*)&sA[wv * 16 + l15][kk * 32 + q * 8];
#pragma unroll
    for (int nt = 0; nt < 16; nt++){
      bf16x8 bv = *(const bf16x8*)(headp + (size_t)((kk * 256 + nt * 16 + l15) * 4 + q) * 8);
      acc[nt] = __builtin_amdgcn_mfma_f32_16x16x32_bf16(av, bv, acc[nt], 0, 0, 0);
    }
  }
#pragma unroll
  for (int nt = 0; nt < 16; nt++){
    int col = nt * 16 + l15;
#pragma unroll
    for (int rr = 0; rr < 4; rr++){
      int row = wv * 16 + q * 4 + rr;
      out[(size_t)(m0 + row) * 256 + col] = acc[nt][rr];
    }
  }
}

// ---------------------------------------------------------------------------

extern "C" void kernel_launch(void* const* d_in, const int* in_sizes, int n_in,
                              void* d_out, int out_size, void* d_ws, size_t ws_size,
                              hipStream_t stream)
{
  const int*   x     = (const int*)d_in[0];
  const float* emb   = (const float*)d_in[1];
  const float* pos   = (const float*)d_in[2];
  const float* lw1   = (const float*)d_in[3];
  const float* lb1   = (const float*)d_in[4];
  const float* lw2   = (const float*)d_in[5];
  const float* lb2   = (const float*)d_in[6];
  const float* llng  = (const float*)d_in[7];
  const float* llnb  = (const float*)d_in[8];
  const float* poolw = (const float*)d_in[9];
  const float* poolb = (const float*)d_in[10];
  const float* mw1   = (const float*)d_in[11];
  const float* mb1   = (const float*)d_in[12];
  const float* mw2   = (const float*)d_in[13];
  const float* mb2   = (const float*)d_in[14];
  const float* uw1   = (const float*)d_in[15];
  const float* ub1   = (const float*)d_in[16];
  const float* uw2   = (const float*)d_in[17];
  const float* ub2   = (const float*)d_in[18];
  const float* mlng  = (const float*)d_in[19];
  const float* mlnb  = (const float*)d_in[20];
  const float* bcw   = (const float*)d_in[21];
  const float* bcb   = (const float*)d_in[22];
  const float* flng  = (const float*)d_in[23];
  const float* flnb  = (const float*)d_in[24];
  const float* headw = (const float*)d_in[25];

  // ws layout (~38.3 MB): packed weights | localB bf16 | bcB bf16
  char* ws = (char*)d_ws;
  u16* wpack = (u16*)ws;
  u16* lw1p  = wpack;
  u16* lw2p  = wpack + 32768;
  u16* poolp = wpack + 65536;
  u16* mw1p  = wpack + 81920;   // P panel; Q panel at +16384
  u16* mw2p  = wpack + 114688;
  u16* uw1p  = wpack + 131072;  // rows 0:128; rows 128:256 at +16384
  u16* uw2p  = wpack + 163840;
  u16* bcp   = wpack + 180224;
  u16* headp = wpack + 196608;
  u16* localB = (u16*)(ws + 524288);       // 131072 x 128 bf16 = 33.55 MB
  u16* bcB    = (u16*)(ws + 34078720);     // 16384 x 128 bf16  = 4.19 MB

  // chunk means live in d_out (dead before k_head, which overwrites all of it)
  u16* summB = (u16*)d_out;                // 16384 x 128 bf16 = 4.19 MB

  k_pack<<<896, 256, 0, stream>>>(lw1, lw2, poolw, mw1, mw2, uw1, uw2, bcw, headw, wpack);
  k_local<<<2048, 256, 0, stream>>>(x, emb, pos, lw1p, lb1, lw2p, lb2, llng, llnb, localB, summB);
  k_rounds<<<256, 320, 0, stream>>>(summB, poolp, poolb, mw1p, mb1, mw2p, mb2,
                                    uw1p, ub1, uw2p, ub2, mlng, mlnb, bcp, bcb, bcB);
  k_head<<<2048, 256, 0, stream>>>(localB, bcB, flng, flnb, headp, (float*)d_out);
}

// Round 3
// 447.519 us; speedup vs baseline: 1.6869x; 1.0728x over previous
//
#include <hip/hip_runtime.h>

typedef unsigned short u16;
typedef __attribute__((ext_vector_type(8))) __bf16 bf16x8;
typedef __attribute__((ext_vector_type(4))) float floatx4;

#define DEV static __device__ __forceinline__

DEV float lo2f(unsigned v){ return __uint_as_float(v << 16); }
DEV float hi2f(unsigned v){ return __uint_as_float(v & 0xffff0000u); }
DEV float bu2f(u16 v){ return __uint_as_float(((unsigned)v) << 16); }
DEV u16 f2b(float f){
  unsigned u = __float_as_uint(f);
  return (u16)((u + 0x7fffu + ((u >> 16) & 1u)) >> 16);
}
// fast erf-gelu: Abramowitz-Stegun 7.1.26, |err_erf| < 1.5e-7
DEV float geluf(float x){
  float u  = x * 0.70710678118654752440f;
  float au = fabsf(u);
  float t  = 1.0f / fmaf(0.3275911f, au, 1.0f);
  float p  = t*(0.254829592f + t*(-0.284496736f + t*(1.421413741f +
             t*(-1.453152027f + t*1.061405429f))));
  float e  = __expf(-au*au);
  float E  = fmaf(-p, e, 1.0f);
  float er = copysignf(E, u);
  return 0.5f * x * (1.0f + er);
}

// ---------------------------------------------------------------------------
// Weight pre-pack: f32 B (K x N row-major) -> bf16 frag layout
//   dst[((kk*N + n)*4 + q)*8 + j] = B[kk*32 + q*8 + j][n]
// mw1/uw1 packed as TWO contiguous N=128 panels each (32 KB per panel).
// ---------------------------------------------------------------------------
__global__ __launch_bounds__(256) void k_pack(
    const float* __restrict__ lw1, const float* __restrict__ lw2, const float* __restrict__ poolw,
    const float* __restrict__ mw1, const float* __restrict__ mw2, const float* __restrict__ uw1,
    const float* __restrict__ uw2, const float* __restrict__ bcw, const float* __restrict__ headw,
    u16* __restrict__ dst)
{
  int b = blockIdx.x;
  const float* src; int N, off;
  if      (b < 128){            src = lw1;  N=256; off = 0;      }
  else if (b < 256){ b -= 128;  src = lw2;  N=128; off = 32768;  }
  else if (b < 320){ b -= 256;  src = poolw;N=128; off = 65536;  }
  else if (b < 384){ b -= 320;  src = mw1;  N=128; off = 81920;  }          // mw1 P half
  else if (b < 448){ b -= 384;  src = mw1 + 16384; N=128; off = 98304; }    // mw1 Q half
  else if (b < 512){ b -= 448;  src = mw2;  N=128; off = 114688; }
  else if (b < 640){ b -= 512;  src = uw1;  N=128; off = 131072; }
  else if (b < 704){ b -= 640;  src = uw2;  N=128; off = 163840; }
  else if (b < 768){ b -= 704;  src = bcw;  N=128; off = 180224; }
  else             { b -= 768;  src = headw;N=256; off = 196608; }
  int e = b * 256 + threadIdx.x;
  int j = e & 7, q = (e >> 3) & 3, rest = e >> 5;
  int n = rest % N, kk = rest / N;
  int k = kk * 32 + q * 8 + j;
  dst[off + e] = f2b(src[k * N + n]);
}

// ---------------------------------------------------------------------------
// k_local: h = emb[tok]+pos[c]; local = h + gelu(LN(h)@lw1+lb1)@lw2+lb2.
// 64 tokens/block, 4 waves. Also emits per-chunk (8-token) mean of the
// f32 local values -> summ (bf16).
// ---------------------------------------------------------------------------
__global__ __launch_bounds__(256) void k_local(
    const int* __restrict__ x, const float* __restrict__ emb, const float* __restrict__ pos,
    const u16* __restrict__ lw1p, const float* __restrict__ lb1,
    const u16* __restrict__ lw2p, const float* __restrict__ lb2,
    const float* __restrict__ g, const float* __restrict__ bb,
    u16* __restrict__ outL, u16* __restrict__ summ)
{
  __shared__ u16 sA[64][136];     // LN'd activations bf16
  __shared__ u16 sY[64][136];     // gelu hidden bf16 (one 128-col half at a time)
  __shared__ int stok[64];
  __shared__ float ps[64][4], ps2[64][4], smu[64], srs[64];
  const int tid = threadIdx.x;
  const int m0 = blockIdx.x * 64;
  if (tid < 64) stok[tid] = x[m0 + tid];
  __syncthreads();
  const int r = tid >> 2, sg = tid & 3;
  float h[32];
  {
    const int tok = stok[r];
    const int c = (m0 + r) & 7;
    const float4* e4 = (const float4*)(emb + (size_t)tok * 128 + sg * 32);
    const float4* p4 = (const float4*)(pos + c * 128 + sg * 32);
    float s = 0.f, s2 = 0.f;
#pragma unroll
    for (int i = 0; i < 8; i++){
      float4 ev = e4[i], pv = p4[i];
      float v0 = ev.x + pv.x, v1 = ev.y + pv.y, v2 = ev.z + pv.z, v3 = ev.w + pv.w;
      h[i * 4 + 0] = v0; h[i * 4 + 1] = v1; h[i * 4 + 2] = v2; h[i * 4 + 3] = v3;
      s += v0 + v1 + v2 + v3;
      s2 += v0 * v0 + v1 * v1 + v2 * v2 + v3 * v3;
    }
    ps[r][sg] = s; ps2[r][sg] = s2;
  }
  __syncthreads();
  if (tid < 64){
    float s  = ps[tid][0] + ps[tid][1] + ps[tid][2] + ps[tid][3];
    float s2 = ps2[tid][0] + ps2[tid][1] + ps2[tid][2] + ps2[tid][3];
    float mu = s * (1.f / 128.f);
    smu[tid] = mu;
    srs[tid] = rsqrtf(s2 * (1.f / 128.f) - mu * mu + 1e-5f);
  }
  __syncthreads();
  {
    float mu = smu[r], rs = srs[r];
#pragma unroll
    for (int i = 0; i < 32; i++){
      int col = sg * 32 + i;
      sA[r][col] = f2b((h[i] - mu) * rs * g[col] + bb[col]);
    }
  }
  __syncthreads();
  const int lane = tid & 63, wv = tid >> 6, l15 = lane & 15, q = lane >> 4;
  // GEMM1 (64x128)@(128x256) and GEMM2 (64x256)@(256x128), N1/K2 split in halves
  floatx4 a2[8];
#pragma unroll
  for (int i = 0; i < 8; i++) a2[i] = (floatx4)(0.0f);
#pragma unroll
  for (int half = 0; half < 2; half++){
    floatx4 a1[8];
#pragma unroll
    for (int i = 0; i < 8; i++) a1[i] = (floatx4)(0.0f);
#pragma unroll
    for (int kk = 0; kk < 4; kk++){
      bf16x8 av = *(const bf16x8*)&sA[wv * 16 + l15][kk * 32 + q * 8];
#pragma unroll
      for (int nt = 0; nt < 8; nt++){
        bf16x8 bv = *(const bf16x8*)(lw1p + (size_t)((kk * 256 + (half * 8 + nt) * 16 + l15) * 4 + q) * 8);
        a1[nt] = __builtin_amdgcn_mfma_f32_16x16x32_bf16(av, bv, a1[nt], 0, 0, 0);
      }
    }
    __syncthreads();   // previous half's sY reads complete before overwrite
#pragma unroll
    for (int nt = 0; nt < 8; nt++){
      int col = nt * 16 + l15;
      float bval = lb1[half * 128 + col];
#pragma unroll
      for (int rr = 0; rr < 4; rr++)
        sY[wv * 16 + q * 4 + rr][col] = f2b(geluf(a1[nt][rr] + bval));
    }
    __syncthreads();   // Y-half writes visible
#pragma unroll
    for (int k = 0; k < 4; k++){
      bf16x8 yv = *(const bf16x8*)&sY[wv * 16 + l15][k * 32 + q * 8];
#pragma unroll
      for (int nt = 0; nt < 8; nt++){
        bf16x8 bv = *(const bf16x8*)(lw2p + (size_t)(((half * 4 + k) * 128 + nt * 16 + l15) * 4 + q) * 8);
        a2[nt] = __builtin_amdgcn_mfma_f32_16x16x32_bf16(yv, bv, a2[nt], 0, 0, 0);
      }
    }
  }
#pragma unroll
  for (int nt = 0; nt < 8; nt++){
    int col = nt * 16 + l15;
    float bval = lb2[col];
    float csum = 0.f;
#pragma unroll
    for (int rr = 0; rr < 4; rr++){
      int row = wv * 16 + q * 4 + rr;
      int gr = m0 + row;
      int tok = stok[row], c = gr & 7;
      float hres = emb[(size_t)tok * 128 + col] + pos[c * 128 + col];
      float v = a2[nt][rr] + bval + hres;
      outL[(size_t)gr * 128 + col] = f2b(v);
      csum += v;
    }
    // rows q*4+rr: q pairs (0,1) and (2,3) form the two chunks of this wave tile
    csum += __shfl_xor(csum, 16, 64);
    if (!(q & 1)){
      int chunk = blockIdx.x * 8 + 2 * wv + (q >> 1);
      summ[(size_t)chunk * 128 + col] = f2b(csum * 0.125f);
    }
  }
}

// ---------------------------------------------------------------------------
// Fused message-passing: pool GEMM + 3 rounds (P,Q,msg,agg,t2a,t2b,upd,LN)
// + bc GEMM. 256 blocks x 640 threads (10 waves). Block owns 64 nodes,
// 80-row panel with 12-node backward halo (halo=0 at batch-row starts).
// R3: double-buffered 32KB weight panels (sW0/sW1) with register prefetch;
// each phase: commit prev prefetch (already drained) -> issue next prefetch
// -> compute. GEMMs split (5 row-tiles x 2 col-halves) over 10 waves, NT=4.
// msg/LN split 8 rows/wave (>=2 waves/SIMD -> VALU can saturate).
// ---------------------------------------------------------------------------
DEV void mma_tile4(floatx4* acc, const u16* Arow, int ap, const u16* W,
                   int colbase, int l15, int q){
  const u16* ar = Arow + l15 * ap + q * 8;
#pragma unroll
  for (int kk = 0; kk < 4; kk++){
    bf16x8 av = *(const bf16x8*)(ar + kk * 32);
#pragma unroll
    for (int nt = 0; nt < 4; nt++){
      bf16x8 bv = *(const bf16x8*)(W + (size_t)((kk * 128 + colbase + nt * 16 + l15) * 4 + q) * 8);
      acc[nt] = __builtin_amdgcn_mfma_f32_16x16x32_bf16(av, bv, acc[nt], 0, 0, 0);
    }
  }
}

template<bool GELU>
DEV void store_tile4(const floatx4* acc, const float* bias, u16* Crow, int cp,
                     int colbase, int l15, int q){
#pragma unroll
  for (int nt = 0; nt < 4; nt++){
    int col = colbase + nt * 16 + l15;
    float bval = bias ? bias[col] : 0.f;
#pragma unroll
    for (int rr = 0; rr < 4; rr++){
      float v = acc[nt][rr] + bval;
      if (GELU) v = geluf(v);
      Crow[(q * 4 + rr) * cp + col] = f2b(v);
    }
  }
}

#define PF(P)    do{ const uint4* gs_ = (const uint4*)(P); \
                     pr0 = gs_[tid]; pr1 = gs_[tid + 640]; pr2 = gs_[tid + 1280]; \
                     if (tid < 128) pr3 = gs_[tid + 1920]; }while(0)
#define COMMIT(S) do{ uint4* ss_ = (uint4*)(S); \
                     ss_[tid] = pr0; ss_[tid + 640] = pr1; ss_[tid + 1280] = pr2; \
                     if (tid < 128) ss_[tid + 1920] = pr3; }while(0)

__global__ __launch_bounds__(640, 1) void k_rounds(
    const u16* __restrict__ summB,
    const u16* __restrict__ poolp, const float* __restrict__ poolb,
    const u16* __restrict__ mw1p, const float* __restrict__ mb1,
    const u16* __restrict__ mw2p, const float* __restrict__ mb2,
    const u16* __restrict__ uw1p, const float* __restrict__ ub1,
    const u16* __restrict__ uw2p, const float* __restrict__ ub2,
    const float* __restrict__ mlng, const float* __restrict__ mlnb,
    const u16* __restrict__ bcp, const float* __restrict__ bcb,
    u16* __restrict__ bcB)
{
  __shared__ __align__(16) u16 sH[80][136];   // hmsg
  __shared__ __align__(16) u16 sPQ[80][264];  // [P|Q]; reused: [agg | upd]
  __shared__ __align__(16) u16 sS[80][136];   // summ; msg means; t2
  __shared__ __align__(16) u16 sW0[16384];    // weight panel double-buffer
  __shared__ __align__(16) u16 sW1[16384];
  const int tid = threadIdx.x;
  const int m0 = blockIdx.x * 64;
  const int halo = (m0 & 1023) ? 12 : 0;
  const int lo = m0 - halo;
  uint4 pr0 = {0,0,0,0}, pr1 = {0,0,0,0}, pr2 = {0,0,0,0}, pr3 = {0,0,0,0};

  PF(poolp);
  // stage summ rows lo..lo+79 (clamped) into sS: 1280 uint4, 2 per thread
  {
#pragma unroll
    for (int k = 0; k < 2; k++){
      int idx = tid + k * 640;
      int rr = idx >> 4, c = idx & 15;
      int node = lo + rr; if (node > 16383) node = 16383;
      *(uint4*)&sS[rr][c * 8] = *(const uint4*)(summB + (size_t)node * 128 + c * 8);
    }
  }
  COMMIT(sW0);        // pool panel (waits its loads; once, at kernel start)
  PF(mw1p);           // P
  __syncthreads();

  const int lane = tid & 63, wv = tid >> 6, l15 = lane & 15, q = lane >> 4;
  const int rt = wv >> 1, ch = wv & 1, colbase = ch * 64;
  const int row0 = rt * 16;
  const int d0 = lane * 2;
  const float b1lo = mb1[d0],  b1hi = mb1[d0 + 1];
  const float glo  = mlng[d0], ghi  = mlng[d0 + 1];
  const float blo  = mlnb[d0], bhi  = mlnb[d0 + 1];

  // phase pool: hmsg = summ @ pool_w + pool_b
  {
    COMMIT(sW1);      // P (drained at last barrier -> no wait)
    PF(mw1p + 16384); // Q
    floatx4 acc[4];
#pragma unroll
    for (int i = 0; i < 4; i++) acc[i] = (floatx4)(0.0f);
    mma_tile4(acc, &sS[row0][0], 136, sW0, colbase, l15, q);
    store_tile4<false>(acc, poolb, &sH[row0][0], 136, colbase, l15, q);
  }
  __syncthreads();

  for (int rnd = 0; rnd < 3; rnd++){
    { // phase P: sPQ[:,0:128] = hmsg @ w1[0:128]
      COMMIT(sW0);    // Q
      PF(mw2p);
      floatx4 acc[4];
#pragma unroll
      for (int i = 0; i < 4; i++) acc[i] = (floatx4)(0.0f);
      mma_tile4(acc, &sH[row0][0], 136, sW1, colbase, l15, q);
      store_tile4<false>(acc, nullptr, &sPQ[row0][0], 264, colbase, l15, q);
    }
    __syncthreads();
    { // phase Q: sPQ[:,128:256] = hmsg @ w1[128:256]
      COMMIT(sW1);    // mw2
      PF(uw1p);       // uw1a
      floatx4 acc[4];
#pragma unroll
      for (int i = 0; i < 4; i++) acc[i] = (floatx4)(0.0f);
      mma_tile4(acc, &sH[row0][0], 136, sW0, colbase, l15, q);
      store_tile4<false>(acc, nullptr, &sPQ[row0][128], 264, colbase, l15, q);
    }
    __syncthreads();
    { // phase msg: s[r] = mean_d gelu(P[r] + Q[r-d] + b1), 8 rows/wave
      for (int it = 0; it < 8; it++){
        int rr = wv * 8 + it;
        int i = (lo + rr) & 1023;
        int nd = (i + 1 < 5) ? i + 1 : 5;
        int ndc = (nd < rr + 1) ? nd : rr + 1;   // clamp for garbage halo rows
        unsigned pv = *(const unsigned*)&sPQ[rr][d0];
        float p0 = lo2f(pv) + b1lo, p1 = hi2f(pv) + b1hi;
        float a0 = 0.f, a1 = 0.f;
        for (int d = 0; d < ndc; d++){
          unsigned qv = *(const unsigned*)&sPQ[rr - d][128 + d0];
          a0 += geluf(p0 + lo2f(qv));
          a1 += geluf(p1 + hi2f(qv));
        }
        float inv = 1.f / (float)nd;
        unsigned pack = (unsigned)f2b(a0 * inv) | (((unsigned)f2b(a1 * inv)) << 16);
        *(unsigned*)&sS[rr][d0] = pack;
      }
    }
    __syncthreads();
    { // phase agg: sPQ[:,0:128] = s @ mw2 + mb2
      COMMIT(sW0);    // uw1a
      PF(uw1p + 16384); // uw1b
      floatx4 acc[4];
#pragma unroll
      for (int i = 0; i < 4; i++) acc[i] = (floatx4)(0.0f);
      mma_tile4(acc, &sS[row0][0], 136, sW1, colbase, l15, q);
      store_tile4<false>(acc, mb2, &sPQ[row0][0], 264, colbase, l15, q);
    }
    __syncthreads();
    floatx4 acc2[4];
    { // phase t2a: acc2 = hmsg @ uw1[0:128]
      COMMIT(sW1);    // uw1b
      PF(uw2p);
#pragma unroll
      for (int i = 0; i < 4; i++) acc2[i] = (floatx4)(0.0f);
      mma_tile4(acc2, &sH[row0][0], 136, sW0, colbase, l15, q);
    }
    __syncthreads();
    { // phase t2b: acc2 += agg @ uw1[128:256]; sS = gelu(acc2 + ub1)
      COMMIT(sW0);    // uw2
      PF(rnd < 2 ? mw1p : bcp);
      mma_tile4(acc2, &sPQ[row0][0], 264, sW1, colbase, l15, q);
      store_tile4<true>(acc2, ub1, &sS[row0][0], 136, colbase, l15, q);
    }
    __syncthreads();
    { // phase upd: sPQ[:,128:256] = t2 @ uw2 + ub2
      COMMIT(sW1);    // next P or bc
      if (rnd < 2) PF(mw1p + 16384);   // next Q
      floatx4 acc[4];
#pragma unroll
      for (int i = 0; i < 4; i++) acc[i] = (floatx4)(0.0f);
      mma_tile4(acc, &sS[row0][0], 136, sW0, colbase, l15, q);
      store_tile4<false>(acc, ub2, &sPQ[row0][128], 264, colbase, l15, q);
    }
    __syncthreads();
    { // phase LN: hmsg = LN(hmsg + upd), 8 rows/wave
      for (int it = 0; it < 8; it++){
        int rr = wv * 8 + it;
        unsigned hv = *(const unsigned*)&sH[rr][d0];
        unsigned uv = *(const unsigned*)&sPQ[rr][128 + d0];
        float x0 = lo2f(hv) + lo2f(uv);
        float x1 = hi2f(hv) + hi2f(uv);
        float s = x0 + x1, s2 = x0 * x0 + x1 * x1;
#pragma unroll
        for (int off = 32; off; off >>= 1){
          s  += __shfl_xor(s, off, 64);
          s2 += __shfl_xor(s2, off, 64);
        }
        float mu = s * (1.f / 128.f);
        float rs = rsqrtf(s2 * (1.f / 128.f) - mu * mu + 1e-5f);
        float y0 = (x0 - mu) * rs * glo + blo;
        float y1 = (x1 - mu) * rs * ghi + bhi;
        unsigned pack = (unsigned)f2b(y0) | (((unsigned)f2b(y1)) << 16);
        *(unsigned*)&sH[rr][d0] = pack;
      }
    }
    __syncthreads();
  }
  { // final: bc = hmsg @ bc_w + bc_b, write owned rows only
    floatx4 acc[4];
#pragma unroll
    for (int i = 0; i < 4; i++) acc[i] = (floatx4)(0.0f);
    mma_tile4(acc, &sH[row0][0], 136, sW1, colbase, l15, q);
#pragma unroll
    for (int nt = 0; nt < 4; nt++){
      int col = colbase + nt * 16 + l15;
      float bval = bcb[col];
#pragma unroll
      for (int rr = 0; rr < 4; rr++){
        int row = row0 + q * 4 + rr;
        if (row >= halo && row < halo + 64){
          int node = lo + row;
          bcB[(size_t)node * 128 + col] = f2b(acc[nt][rr] + bval);
        }
      }
    }
  }
}

// ---------------------------------------------------------------------------
// k_head: out = LN(local + bc[chunk]) @ head_w  (131072 x 128 x 256), f32 out
// ---------------------------------------------------------------------------
__global__ __launch_bounds__(256) void k_head(
    const u16* __restrict__ localL, const u16* __restrict__ bcB,
    const float* __restrict__ g, const float* __restrict__ bb,
    const u16* __restrict__ headp, float* __restrict__ out)
{
  __shared__ u16 sA[64][136];
  __shared__ float ps[64][4], ps2[64][4], smu[64], srs[64];
  const int tid = threadIdx.x;
  const int m0 = blockIdx.x * 64;
  const int r = tid >> 2, sg = tid & 3;
  float h[32];
  {
    const int gr = m0 + r;
    const int ch = gr >> 3;
    const uint4* l4 = (const uint4*)(localL + (size_t)gr * 128 + sg * 32);
    const uint4* c4 = (const uint4*)(bcB + (size_t)ch * 128 + sg * 32);
    float s = 0.f, s2 = 0.f;
#pragma unroll
    for (int i = 0; i < 4; i++){
      uint4 lv = l4[i], cv = c4[i];
      unsigned lw[4] = {lv.x, lv.y, lv.z, lv.w}, cw[4] = {cv.x, cv.y, cv.z, cv.w};
#pragma unroll
      for (int j = 0; j < 4; j++){
        float v0 = lo2f(lw[j]) + lo2f(cw[j]);
        float v1 = hi2f(lw[j]) + hi2f(cw[j]);
        h[i * 8 + j * 2] = v0; h[i * 8 + j * 2 + 1] = v1;
        s += v0 + v1; s2 += v0 * v0 + v1 * v1;
      }
    }
    ps[r][sg] = s; ps2[r][sg] = s2;
  }
  __syncthreads();
  if (tid < 64){
    float s  = ps[tid][0] + ps[tid][1] + ps[tid][2] + ps[tid][3];
    float s2 = ps2[tid][0] + ps2[tid][1] + ps2[tid][2] + ps2[tid][3];
    float mu = s * (1.f / 128.f);
    smu[tid] = mu;
    srs[tid] = rsqrtf(s2 * (1.f / 128.f) - mu * mu + 1e-5f);
  }
  __syncthreads();
  {
    float mu = smu[r], rs = srs[r];
#pragma unroll
    for (int i = 0; i < 32; i++){
      int col = sg * 32 + i;
      sA[r][col] = f2b((h[i] - mu) * rs * g[col] + bb[col]);
    }
  }
  __syncthreads();
  const int lane = tid & 63, wv = tid >> 6, l15 = lane & 15, q = lane >> 4;
  floatx4 acc[16];
#pragma unroll
  for (int i = 0; i < 16; i++) acc[i] = (floatx4)(0.0f);
#pragma unroll
  for (int kk = 0; kk < 4; kk++){
    bf16x8 av = *(const bf16x8*)&sA[wv * 16 + l15][kk * 32 + q * 8];
#pragma unroll
    for (int nt = 0; nt < 16; nt++){
      bf16x8 bv = *(const bf16x8*)(headp + (size_t)((kk * 256 + nt * 16 + l15) * 4 + q) * 8);
      acc[nt] = __builtin_amdgcn_mfma_f32_16x16x32_bf16(av, bv, acc[nt], 0, 0, 0);
    }
  }
#pragma unroll
  for (int nt = 0; nt < 16; nt++){
    int col = nt * 16 + l15;
#pragma unroll
    for (int rr = 0; rr < 4; rr++){
      int row = wv * 16 + q * 4 + rr;
      out[(size_t)(m0 + row) * 256 + col] = acc[nt][rr];
    }
  }
}

// ---------------------------------------------------------------------------

extern "C" void kernel_launch(void* const* d_in, const int* in_sizes, int n_in,
                              void* d_out, int out_size, void* d_ws, size_t ws_size,
                              hipStream_t stream)
{
  const int*   x     = (const int*)d_in[0];
  const float* emb   = (const float*)d_in[1];
  const float* pos   = (const float*)d_in[2];
  const float* lw1   = (const float*)d_in[3];
  const float* lb1   = (const float*)d_in[4];
  const float* lw2   = (const float*)d_in[5];
  const float* lb2   = (const float*)d_in[6];
  const float* llng  = (const float*)d_in[7];
  const float* llnb  = (const float*)d_in[8];
  const float* poolw = (const float*)d_in[9];
  const float* poolb = (const float*)d_in[10];
  const float* mw1   = (const float*)d_in[11];
  const float* mb1   = (const float*)d_in[12];
  const float* mw2   = (const float*)d_in[13];
  const float* mb2   = (const float*)d_in[14];
  const float* uw1   = (const float*)d_in[15];
  const float* ub1   = (const float*)d_in[16];
  const float* uw2   = (const float*)d_in[17];
  const float* ub2   = (const float*)d_in[18];
  const float* mlng  = (const float*)d_in[19];
  const float* mlnb  = (const float*)d_in[20];
  const float* bcw   = (const float*)d_in[21];
  const float* bcb   = (const float*)d_in[22];
  const float* flng  = (const float*)d_in[23];
  const float* flnb  = (const float*)d_in[24];
  const float* headw = (const float*)d_in[25];

  // ws layout (~38.3 MB): packed weights | localB bf16 | bcB bf16
  char* ws = (char*)d_ws;
  u16* wpack = (u16*)ws;
  u16* lw1p  = wpack;
  u16* lw2p  = wpack + 32768;
  u16* poolp = wpack + 65536;
  u16* mw1p  = wpack + 81920;   // P panel; Q panel at +16384
  u16* mw2p  = wpack + 114688;
  u16* uw1p  = wpack + 131072;  // rows 0:128; rows 128:256 at +16384
  u16* uw2p  = wpack + 163840;
  u16* bcp   = wpack + 180224;
  u16* headp = wpack + 196608;
  u16* localB = (u16*)(ws + 524288);       // 131072 x 128 bf16 = 33.55 MB
  u16* bcB    = (u16*)(ws + 34078720);     // 16384 x 128 bf16  = 4.19 MB

  // chunk means live in d_out (dead before k_head, which overwrites all of it)
  u16* summB = (u16*)d_out;                // 16384 x 128 bf16 = 4.19 MB

  k_pack<<<896, 256, 0, stream>>>(lw1, lw2, poolw, mw1, mw2, uw1, uw2, bcw, headw, wpack);
  k_local<<<2048, 256, 0, stream>>>(x, emb, pos, lw1p, lb1, lw2p, lb2, llng, llnb, localB, summB);
  k_rounds<<<256, 640, 0, stream>>>(summB, poolp, poolb, mw1p, mb1, mw2p, mb2,
                                    uw1p, ub1, uw2p, ub2, mlng, mlnb, bcp, bcb, bcB);
  k_head<<<2048, 256, 0, stream>>>(localB, bcB, flng, flnb, headp, (float*)d_out);
}

// Round 5
// 446.318 us; speedup vs baseline: 1.6914x; 1.0027x over previous
//
#include <hip/hip_runtime.h>

typedef unsigned short u16;
typedef __attribute__((ext_vector_type(8))) __bf16 bf16x8;
typedef __attribute__((ext_vector_type(4))) float floatx4;

#define DEV static __device__ __forceinline__

DEV float lo2f(unsigned v){ return __uint_as_float(v << 16); }
DEV float hi2f(unsigned v){ return __uint_as_float(v & 0xffff0000u); }
DEV float bu2f(u16 v){ return __uint_as_float(((unsigned)v) << 16); }
DEV u16 f2b(float f){
  unsigned u = __float_as_uint(f);
  return (u16)((u + 0x7fffu + ((u >> 16) & 1u)) >> 16);
}
// fast erf-gelu: Abramowitz-Stegun 7.1.26, |err_erf| < 1.5e-7
DEV float geluf(float x){
  float u  = x * 0.70710678118654752440f;
  float au = fabsf(u);
  float t  = 1.0f / fmaf(0.3275911f, au, 1.0f);
  float p  = t*(0.254829592f + t*(-0.284496736f + t*(1.421413741f +
             t*(-1.453152027f + t*1.061405429f))));
  float e  = __expf(-au*au);
  float E  = fmaf(-p, e, 1.0f);
  float er = copysignf(E, u);
  return 0.5f * x * (1.0f + er);
}

// ---------------------------------------------------------------------------
// Weight pre-pack: f32 B (K x N row-major) -> bf16 frag layout
//   dst[((kk*N + n)*4 + q)*8 + j] = B[kk*32 + q*8 + j][n]
// mw1/uw1 packed as TWO contiguous N=128 panels each (32 KB per panel).
// ---------------------------------------------------------------------------
__global__ __launch_bounds__(256) void k_pack(
    const float* __restrict__ lw1, const float* __restrict__ lw2, const float* __restrict__ poolw,
    const float* __restrict__ mw1, const float* __restrict__ mw2, const float* __restrict__ uw1,
    const float* __restrict__ uw2, const float* __restrict__ bcw, const float* __restrict__ headw,
    u16* __restrict__ dst)
{
  int b = blockIdx.x;
  const float* src; int N, off;
  if      (b < 128){            src = lw1;  N=256; off = 0;      }
  else if (b < 256){ b -= 128;  src = lw2;  N=128; off = 32768;  }
  else if (b < 320){ b -= 256;  src = poolw;N=128; off = 65536;  }
  else if (b < 384){ b -= 320;  src = mw1;  N=128; off = 81920;  }          // mw1 P half
  else if (b < 448){ b -= 384;  src = mw1 + 16384; N=128; off = 98304; }    // mw1 Q half
  else if (b < 512){ b -= 448;  src = mw2;  N=128; off = 114688; }
  else if (b < 640){ b -= 512;  src = uw1;  N=128; off = 131072; }
  else if (b < 704){ b -= 640;  src = uw2;  N=128; off = 163840; }
  else if (b < 768){ b -= 704;  src = bcw;  N=128; off = 180224; }
  else             { b -= 768;  src = headw;N=256; off = 196608; }
  int e = b * 256 + threadIdx.x;
  int j = e & 7, q = (e >> 3) & 3, rest = e >> 5;
  int n = rest % N, kk = rest / N;
  int k = kk * 32 + q * 8 + j;
  dst[off + e] = f2b(src[k * N + n]);
}

// ---------------------------------------------------------------------------
// k_local (R3-proven structure): h = emb[tok]+pos[c];
// local = h + gelu(LN(h)@lw1+lb1)@lw2+lb2. 64 tokens/block, 4 waves.
// Also emits per-chunk (8-token) mean of the f32 local values -> summ.
// R5 change: epilogue residual loads (emb+pos) hoisted into hre[8][4]
// registers BEFORE the GEMM half-loop so the gather hides under MFMA.
// ---------------------------------------------------------------------------
__global__ __launch_bounds__(256) void k_local(
    const int* __restrict__ x, const float* __restrict__ emb, const float* __restrict__ pos,
    const u16* __restrict__ lw1p, const float* __restrict__ lb1,
    const u16* __restrict__ lw2p, const float* __restrict__ lb2,
    const float* __restrict__ g, const float* __restrict__ bb,
    u16* __restrict__ outL, u16* __restrict__ summ)
{
  __shared__ u16 sA[64][136];     // LN'd activations bf16
  __shared__ u16 sY[64][136];     // gelu hidden bf16 (one 128-col half at a time)
  __shared__ int stok[64];
  __shared__ float ps[64][4], ps2[64][4], smu[64], srs[64];
  const int tid = threadIdx.x;
  const int m0 = blockIdx.x * 64;
  if (tid < 64) stok[tid] = x[m0 + tid];
  __syncthreads();
  const int r = tid >> 2, sg = tid & 3;
  float h[32];
  {
    const int tok = stok[r];
    const int c = (m0 + r) & 7;
    const float4* e4 = (const float4*)(emb + (size_t)tok * 128 + sg * 32);
    const float4* p4 = (const float4*)(pos + c * 128 + sg * 32);
    float s = 0.f, s2 = 0.f;
#pragma unroll
    for (int i = 0; i < 8; i++){
      float4 ev = e4[i], pv = p4[i];
      float v0 = ev.x + pv.x, v1 = ev.y + pv.y, v2 = ev.z + pv.z, v3 = ev.w + pv.w;
      h[i * 4 + 0] = v0; h[i * 4 + 1] = v1; h[i * 4 + 2] = v2; h[i * 4 + 3] = v3;
      s += v0 + v1 + v2 + v3;
      s2 += v0 * v0 + v1 * v1 + v2 * v2 + v3 * v3;
    }
    ps[r][sg] = s; ps2[r][sg] = s2;
  }
  __syncthreads();
  if (tid < 64){
    float s  = ps[tid][0] + ps[tid][1] + ps[tid][2] + ps[tid][3];
    float s2 = ps2[tid][0] + ps2[tid][1] + ps2[tid][2] + ps2[tid][3];
    float mu = s * (1.f / 128.f);
    smu[tid] = mu;
    srs[tid] = rsqrtf(s2 * (1.f / 128.f) - mu * mu + 1e-5f);
  }
  __syncthreads();
  {
    float mu = smu[r], rs = srs[r];
#pragma unroll
    for (int i = 0; i < 32; i++){
      int col = sg * 32 + i;
      sA[r][col] = f2b((h[i] - mu) * rs * g[col] + bb[col]);
    }
  }
  __syncthreads();
  const int lane = tid & 63, wv = tid >> 6, l15 = lane & 15, q = lane >> 4;
  // R5: hoist epilogue residuals (same values, same adds; loads issue early
  // and their latency hides under the GEMM half-loop)
  float hre[8][4];
#pragma unroll
  for (int nt = 0; nt < 8; nt++){
    int col = nt * 16 + l15;
#pragma unroll
    for (int rr = 0; rr < 4; rr++){
      int row = wv * 16 + q * 4 + rr;
      int gr = m0 + row;
      hre[nt][rr] = emb[(size_t)stok[row] * 128 + col] + pos[(gr & 7) * 128 + col];
    }
  }
  // GEMM1 (64x128)@(128x256) and GEMM2 (64x256)@(256x128), N1/K2 split in halves
  floatx4 a2[8];
#pragma unroll
  for (int i = 0; i < 8; i++) a2[i] = (floatx4)(0.0f);
#pragma unroll
  for (int half = 0; half < 2; half++){
    floatx4 a1[8];
#pragma unroll
    for (int i = 0; i < 8; i++) a1[i] = (floatx4)(0.0f);
#pragma unroll
    for (int kk = 0; kk < 4; kk++){
      bf16x8 av = *(const bf16x8*)&sA[wv * 16 + l15][kk * 32 + q * 8];
#pragma unroll
      for (int nt = 0; nt < 8; nt++){
        bf16x8 bv = *(const bf16x8*)(lw1p + (size_t)((kk * 256 + (half * 8 + nt) * 16 + l15) * 4 + q) * 8);
        a1[nt] = __builtin_amdgcn_mfma_f32_16x16x32_bf16(av, bv, a1[nt], 0, 0, 0);
      }
    }
    __syncthreads();   // previous half's sY reads complete before overwrite
#pragma unroll
    for (int nt = 0; nt < 8; nt++){
      int col = nt * 16 + l15;
      float bval = lb1[half * 128 + col];
#pragma unroll
      for (int rr = 0; rr < 4; rr++)
        sY[wv * 16 + q * 4 + rr][col] = f2b(geluf(a1[nt][rr] + bval));
    }
    __syncthreads();   // Y-half writes visible
#pragma unroll
    for (int k = 0; k < 4; k++){
      bf16x8 yv = *(const bf16x8*)&sY[wv * 16 + l15][k * 32 + q * 8];
#pragma unroll
      for (int nt = 0; nt < 8; nt++){
        bf16x8 bv = *(const bf16x8*)(lw2p + (size_t)(((half * 4 + k) * 128 + nt * 16 + l15) * 4 + q) * 8);
        a2[nt] = __builtin_amdgcn_mfma_f32_16x16x32_bf16(yv, bv, a2[nt], 0, 0, 0);
      }
    }
  }
#pragma unroll
  for (int nt = 0; nt < 8; nt++){
    int col = nt * 16 + l15;
    float bval = lb2[col];
    float csum = 0.f;
#pragma unroll
    for (int rr = 0; rr < 4; rr++){
      int row = wv * 16 + q * 4 + rr;
      int gr = m0 + row;
      float v = a2[nt][rr] + bval + hre[nt][rr];
      outL[(size_t)gr * 128 + col] = f2b(v);
      csum += v;
    }
    // rows q*4+rr: q pairs (0,1) and (2,3) form the two chunks of this wave tile
    csum += __shfl_xor(csum, 16, 64);
    if (!(q & 1)){
      int chunk = blockIdx.x * 8 + 2 * wv + (q >> 1);
      summ[(size_t)chunk * 128 + col] = f2b(csum * 0.125f);
    }
  }
}

// ---------------------------------------------------------------------------
// Fused message-passing (unchanged from R3): pool GEMM + 3 rounds + bc GEMM.
// 256 blocks x 640 threads, double-buffered weight panels, reg prefetch.
// ---------------------------------------------------------------------------
DEV void mma_tile4(floatx4* acc, const u16* Arow, int ap, const u16* W,
                   int colbase, int l15, int q){
  const u16* ar = Arow + l15 * ap + q * 8;
#pragma unroll
  for (int kk = 0; kk < 4; kk++){
    bf16x8 av = *(const bf16x8*)(ar + kk * 32);
#pragma unroll
    for (int nt = 0; nt < 4; nt++){
      bf16x8 bv = *(const bf16x8*)(W + (size_t)((kk * 128 + colbase + nt * 16 + l15) * 4 + q) * 8);
      acc[nt] = __builtin_amdgcn_mfma_f32_16x16x32_bf16(av, bv, acc[nt], 0, 0, 0);
    }
  }
}

template<bool GELU>
DEV void store_tile4(const floatx4* acc, const float* bias, u16* Crow, int cp,
                     int colbase, int l15, int q){
#pragma unroll
  for (int nt = 0; nt < 4; nt++){
    int col = colbase + nt * 16 + l15;
    float bval = bias ? bias[col] : 0.f;
#pragma unroll
    for (int rr = 0; rr < 4; rr++){
      float v = acc[nt][rr] + bval;
      if (GELU) v = geluf(v);
      Crow[(q * 4 + rr) * cp + col] = f2b(v);
    }
  }
}

#define PF(P)    do{ const uint4* gs_ = (const uint4*)(P); \
                     pr0 = gs_[tid]; pr1 = gs_[tid + 640]; pr2 = gs_[tid + 1280]; \
                     if (tid < 128) pr3 = gs_[tid + 1920]; }while(0)
#define COMMIT(S) do{ uint4* ss_ = (uint4*)(S); \
                     ss_[tid] = pr0; ss_[tid + 640] = pr1; ss_[tid + 1280] = pr2; \
                     if (tid < 128) ss_[tid + 1920] = pr3; }while(0)

__global__ __launch_bounds__(640, 1) void k_rounds(
    const u16* __restrict__ summB,
    const u16* __restrict__ poolp, const float* __restrict__ poolb,
    const u16* __restrict__ mw1p, const float* __restrict__ mb1,
    const u16* __restrict__ mw2p, const float* __restrict__ mb2,
    const u16* __restrict__ uw1p, const float* __restrict__ ub1,
    const u16* __restrict__ uw2p, const float* __restrict__ ub2,
    const float* __restrict__ mlng, const float* __restrict__ mlnb,
    const u16* __restrict__ bcp, const float* __restrict__ bcb,
    u16* __restrict__ bcB)
{
  __shared__ __align__(16) u16 sH[80][136];   // hmsg
  __shared__ __align__(16) u16 sPQ[80][264];  // [P|Q]; reused: [agg | upd]
  __shared__ __align__(16) u16 sS[80][136];   // summ; msg means; t2
  __shared__ __align__(16) u16 sW0[16384];    // weight panel double-buffer
  __shared__ __align__(16) u16 sW1[16384];
  const int tid = threadIdx.x;
  const int m0 = blockIdx.x * 64;
  const int halo = (m0 & 1023) ? 12 : 0;
  const int lo = m0 - halo;
  uint4 pr0 = {0,0,0,0}, pr1 = {0,0,0,0}, pr2 = {0,0,0,0}, pr3 = {0,0,0,0};

  PF(poolp);
  // stage summ rows lo..lo+79 (clamped) into sS: 1280 uint4, 2 per thread
  {
#pragma unroll
    for (int k = 0; k < 2; k++){
      int idx = tid + k * 640;
      int rr = idx >> 4, c = idx & 15;
      int node = lo + rr; if (node > 16383) node = 16383;
      *(uint4*)&sS[rr][c * 8] = *(const uint4*)(summB + (size_t)node * 128 + c * 8);
    }
  }
  COMMIT(sW0);        // pool panel (waits its loads; once, at kernel start)
  PF(mw1p);           // P
  __syncthreads();

  const int lane = tid & 63, wv = tid >> 6, l15 = lane & 15, q = lane >> 4;
  const int rt = wv >> 1, ch = wv & 1, colbase = ch * 64;
  const int row0 = rt * 16;
  const int d0 = lane * 2;
  const float b1lo = mb1[d0],  b1hi = mb1[d0 + 1];
  const float glo  = mlng[d0], ghi  = mlng[d0 + 1];
  const float blo  = mlnb[d0], bhi  = mlnb[d0 + 1];

  // phase pool: hmsg = summ @ pool_w + pool_b
  {
    COMMIT(sW1);      // P (drained at last barrier -> no wait)
    PF(mw1p + 16384); // Q
    floatx4 acc[4];
#pragma unroll
    for (int i = 0; i < 4; i++) acc[i] = (floatx4)(0.0f);
    mma_tile4(acc, &sS[row0][0], 136, sW0, colbase, l15, q);
    store_tile4<false>(acc, poolb, &sH[row0][0], 136, colbase, l15, q);
  }
  __syncthreads();

  for (int rnd = 0; rnd < 3; rnd++){
    { // phase P: sPQ[:,0:128] = hmsg @ w1[0:128]
      COMMIT(sW0);    // Q
      PF(mw2p);
      floatx4 acc[4];
#pragma unroll
      for (int i = 0; i < 4; i++) acc[i] = (floatx4)(0.0f);
      mma_tile4(acc, &sH[row0][0], 136, sW1, colbase, l15, q);
      store_tile4<false>(acc, nullptr, &sPQ[row0][0], 264, colbase, l15, q);
    }
    __syncthreads();
    { // phase Q: sPQ[:,128:256] = hmsg @ w1[128:256]
      COMMIT(sW1);    // mw2
      PF(uw1p);       // uw1a
      floatx4 acc[4];
#pragma unroll
      for (int i = 0; i < 4; i++) acc[i] = (floatx4)(0.0f);
      mma_tile4(acc, &sH[row0][0], 136, sW0, colbase, l15, q);
      store_tile4<false>(acc, nullptr, &sPQ[row0][128], 264, colbase, l15, q);
    }
    __syncthreads();
    { // phase msg: s[r] = mean_d gelu(P[r] + Q[r-d] + b1), 8 rows/wave
      for (int it = 0; it < 8; it++){
        int rr = wv * 8 + it;
        int i = (lo + rr) & 1023;
        int nd = (i + 1 < 5) ? i + 1 : 5;
        int ndc = (nd < rr + 1) ? nd : rr + 1;   // clamp for garbage halo rows
        unsigned pv = *(const unsigned*)&sPQ[rr][d0];
        float p0 = lo2f(pv) + b1lo, p1 = hi2f(pv) + b1hi;
        float a0 = 0.f, a1 = 0.f;
        for (int d = 0; d < ndc; d++){
          unsigned qv = *(const unsigned*)&sPQ[rr - d][128 + d0];
          a0 += geluf(p0 + lo2f(qv));
          a1 += geluf(p1 + hi2f(qv));
        }
        float inv = 1.f / (float)nd;
        unsigned pack = (unsigned)f2b(a0 * inv) | (((unsigned)f2b(a1 * inv)) << 16);
        *(unsigned*)&sS[rr][d0] = pack;
      }
    }
    __syncthreads();
    { // phase agg: sPQ[:,0:128] = s @ mw2 + mb2
      COMMIT(sW0);    // uw1a
      PF(uw1p + 16384); // uw1b
      floatx4 acc[4];
#pragma unroll
      for (int i = 0; i < 4; i++) acc[i] = (floatx4)(0.0f);
      mma_tile4(acc, &sS[row0][0], 136, sW1, colbase, l15, q);
      store_tile4<false>(acc, mb2, &sPQ[row0][0], 264, colbase, l15, q);
    }
    __syncthreads();
    floatx4 acc2[4];
    { // phase t2a: acc2 = hmsg @ uw1[0:128]
      COMMIT(sW1);    // uw1b
      PF(uw2p);
#pragma unroll
      for (int i = 0; i < 4; i++) acc2[i] = (floatx4)(0.0f);
      mma_tile4(acc2, &sH[row0][0], 136, sW0, colbase, l15, q);
    }
    __syncthreads();
    { // phase t2b: acc2 += agg @ uw1[128:256]; sS = gelu(acc2 + ub1)
      COMMIT(sW0);    // uw2
      PF(rnd < 2 ? mw1p : bcp);
      mma_tile4(acc2, &sPQ[row0][0], 264, sW1, colbase, l15, q);
      store_tile4<true>(acc2, ub1, &sS[row0][0], 136, colbase, l15, q);
    }
    __syncthreads();
    { // phase upd: sPQ[:,128:256] = t2 @ uw2 + ub2
      COMMIT(sW1);    // next P or bc
      if (rnd < 2) PF(mw1p + 16384);   // next Q
      floatx4 acc[4];
#pragma unroll
      for (int i = 0; i < 4; i++) acc[i] = (floatx4)(0.0f);
      mma_tile4(acc, &sS[row0][0], 136, sW0, colbase, l15, q);
      store_tile4<false>(acc, ub2, &sPQ[row0][128], 264, colbase, l15, q);
    }
    __syncthreads();
    { // phase LN: hmsg = LN(hmsg + upd), 8 rows/wave
      for (int it = 0; it < 8; it++){
        int rr = wv * 8 + it;
        unsigned hv = *(const unsigned*)&sH[rr][d0];
        unsigned uv = *(const unsigned*)&sPQ[rr][128 + d0];
        float x0 = lo2f(hv) + lo2f(uv);
        float x1 = hi2f(hv) + hi2f(uv);
        float s = x0 + x1, s2 = x0 * x0 + x1 * x1;
#pragma unroll
        for (int off = 32; off; off >>= 1){
          s  += __shfl_xor(s, off, 64);
          s2 += __shfl_xor(s2, off, 64);
        }
        float mu = s * (1.f / 128.f);
        float rs = rsqrtf(s2 * (1.f / 128.f) - mu * mu + 1e-5f);
        float y0 = (x0 - mu) * rs * glo + blo;
        float y1 = (x1 - mu) * rs * ghi + bhi;
        unsigned pack = (unsigned)f2b(y0) | (((unsigned)f2b(y1)) << 16);
        *(unsigned*)&sH[rr][d0] = pack;
      }
    }
    __syncthreads();
  }
  { // final: bc = hmsg @ bc_w + bc_b, write owned rows only
    floatx4 acc[4];
#pragma unroll
    for (int i = 0; i < 4; i++) acc[i] = (floatx4)(0.0f);
    mma_tile4(acc, &sH[row0][0], 136, sW1, colbase, l15, q);
#pragma unroll
    for (int nt = 0; nt < 4; nt++){
      int col = colbase + nt * 16 + l15;
      float bval = bcb[col];
#pragma unroll
      for (int rr = 0; rr < 4; rr++){
        int row = row0 + q * 4 + rr;
        if (row >= halo && row < halo + 64){
          int node = lo + row;
          bcB[(size_t)node * 128 + col] = f2b(acc[nt][rr] + bval);
        }
      }
    }
  }
}

// ---------------------------------------------------------------------------
// k_head (R3-proven structure, R5 column-split): out = LN(local+bc)@head_w.
// Grid 4096: block (b>>1) owns 64 rows, (b&1) selects 128-col half. LN is
// recomputed per half (cheap, idempotent); GEMM/store chain and acc regs
// halve, doubling schedulable blocks for latency overlap.
// ---------------------------------------------------------------------------
__global__ __launch_bounds__(256) void k_head(
    const u16* __restrict__ localL, const u16* __restrict__ bcB,
    const float* __restrict__ g, const float* __restrict__ bb,
    const u16* __restrict__ headp, float* __restrict__ out)
{
  __shared__ u16 sA[64][136];
  __shared__ float ps[64][4], ps2[64][4], smu[64], srs[64];
  const int tid = threadIdx.x;
  const int m0 = (blockIdx.x >> 1) * 64;
  const int nh = blockIdx.x & 1;
  const int r = tid >> 2, sg = tid & 3;
  float h[32];
  {
    const int gr = m0 + r;
    const int ch = gr >> 3;
    const uint4* l4 = (const uint4*)(localL + (size_t)gr * 128 + sg * 32);
    const uint4* c4 = (const uint4*)(bcB + (size_t)ch * 128 + sg * 32);
    float s = 0.f, s2 = 0.f;
#pragma unroll
    for (int i = 0; i < 4; i++){
      uint4 lv = l4[i], cv = c4[i];
      unsigned lw[4] = {lv.x, lv.y, lv.z, lv.w}, cw[4] = {cv.x, cv.y, cv.z, cv.w};
#pragma unroll
      for (int j = 0; j < 4; j++){
        float v0 = lo2f(lw[j]) + lo2f(cw[j]);
        float v1 = hi2f(lw[j]) + hi2f(cw[j]);
        h[i * 8 + j * 2] = v0; h[i * 8 + j * 2 + 1] = v1;
        s += v0 + v1; s2 += v0 * v0 + v1 * v1;
      }
    }
    ps[r][sg] = s; ps2[r][sg] = s2;
  }
  __syncthreads();
  if (tid < 64){
    float s  = ps[tid][0] + ps[tid][1] + ps[tid][2] + ps[tid][3];
    float s2 = ps2[tid][0] + ps2[tid][1] + ps2[tid][2] + ps2[tid][3];
    float mu = s * (1.f / 128.f);
    smu[tid] = mu;
    srs[tid] = rsqrtf(s2 * (1.f / 128.f) - mu * mu + 1e-5f);
  }
  __syncthreads();
  {
    float mu = smu[r], rs = srs[r];
#pragma unroll
    for (int i = 0; i < 32; i++){
      int col = sg * 32 + i;
      sA[r][col] = f2b((h[i] - mu) * rs * g[col] + bb[col]);
    }
  }
  __syncthreads();
  const int lane = tid & 63, wv = tid >> 6, l15 = lane & 15, q = lane >> 4;
  floatx4 acc[8];
#pragma unroll
  for (int i = 0; i < 8; i++) acc[i] = (floatx4)(0.0f);
#pragma unroll
  for (int kk = 0; kk < 4; kk++){
    bf16x8 av = *(const bf16x8*)&sA[wv * 16 + l15][kk * 32 + q * 8];
#pragma unroll
    for (int nt = 0; nt < 8; nt++){
      bf16x8 bv = *(const bf16x8*)(headp + (size_t)((kk * 256 + nh * 128 + nt * 16 + l15) * 4 + q) * 8);
      acc[nt] = __builtin_amdgcn_mfma_f32_16x16x32_bf16(av, bv, acc[nt], 0, 0, 0);
    }
  }
#pragma unroll
  for (int nt = 0; nt < 8; nt++){
    int col = nh * 128 + nt * 16 + l15;
#pragma unroll
    for (int rr = 0; rr < 4; rr++){
      int row = wv * 16 + q * 4 + rr;
      out[(size_t)(m0 + row) * 256 + col] = acc[nt][rr];
    }
  }
}

// ---------------------------------------------------------------------------

extern "C" void kernel_launch(void* const* d_in, const int* in_sizes, int n_in,
                              void* d_out, int out_size, void* d_ws, size_t ws_size,
                              hipStream_t stream)
{
  const int*   x     = (const int*)d_in[0];
  const float* emb   = (const float*)d_in[1];
  const float* pos   = (const float*)d_in[2];
  const float* lw1   = (const float*)d_in[3];
  const float* lb1   = (const float*)d_in[4];
  const float* lw2   = (const float*)d_in[5];
  const float* lb2   = (const float*)d_in[6];
  const float* llng  = (const float*)d_in[7];
  const float* llnb  = (const float*)d_in[8];
  const float* poolw = (const float*)d_in[9];
  const float* poolb = (const float*)d_in[10];
  const float* mw1   = (const float*)d_in[11];
  const float* mb1   = (const float*)d_in[12];
  const float* mw2   = (const float*)d_in[13];
  const float* mb2   = (const float*)d_in[14];
  const float* uw1   = (const float*)d_in[15];
  const float* ub1   = (const float*)d_in[16];
  const float* uw2   = (const float*)d_in[17];
  const float* ub2   = (const float*)d_in[18];
  const float* mlng  = (const float*)d_in[19];
  const float* mlnb  = (const float*)d_in[20];
  const float* bcw   = (const float*)d_in[21];
  const float* bcb   = (const float*)d_in[22];
  const float* flng  = (const float*)d_in[23];
  const float* flnb  = (const float*)d_in[24];
  const float* headw = (const float*)d_in[25];

  // ws layout (~38.3 MB): packed weights | localB bf16 | bcB bf16
  char* ws = (char*)d_ws;
  u16* wpack = (u16*)ws;
  u16* lw1p  = wpack;
  u16* lw2p  = wpack + 32768;
  u16* poolp = wpack + 65536;
  u16* mw1p  = wpack + 81920;   // P panel; Q panel at +16384
  u16* mw2p  = wpack + 114688;
  u16* uw1p  = wpack + 131072;  // rows 0:128; rows 128:256 at +16384
  u16* uw2p  = wpack + 163840;
  u16* bcp   = wpack + 180224;
  u16* headp = wpack + 196608;
  u16* localB = (u16*)(ws + 524288);       // 131072 x 128 bf16 = 33.55 MB
  u16* bcB    = (u16*)(ws + 34078720);     // 16384 x 128 bf16  = 4.19 MB

  // chunk means live in d_out (dead before k_head, which overwrites all of it)
  u16* summB = (u16*)d_out;                // 16384 x 128 bf16 = 4.19 MB

  k_pack<<<896, 256, 0, stream>>>(lw1, lw2, poolw, mw1, mw2, uw1, uw2, bcw, headw, wpack);
  k_local<<<2048, 256, 0, stream>>>(x, emb, pos, lw1p, lb1, lw2p, lb2, llng, llnb, localB, summB);
  k_rounds<<<256, 640, 0, stream>>>(summB, poolp, poolb, mw1p, mb1, mw2p, mb2,
                                    uw1p, ub1, uw2p, ub2, mlng, mlnb, bcp, bcb, bcB);
  k_head<<<4096, 256, 0, stream>>>(localB, bcB, flng, flnb, headp, (float*)d_out);
}

// Round 6
// 423.529 us; speedup vs baseline: 1.7824x; 1.0538x over previous
//
#include <hip/hip_runtime.h>

typedef unsigned short u16;
typedef __attribute__((ext_vector_type(8))) __bf16 bf16x8;
typedef __attribute__((ext_vector_type(4))) float floatx4;

#define DEV static __device__ __forceinline__

DEV float lo2f(unsigned v){ return __uint_as_float(v << 16); }
DEV float hi2f(unsigned v){ return __uint_as_float(v & 0xffff0000u); }
DEV u16 f2b(float f){
  unsigned u = __float_as_uint(f);
  return (u16)((u + 0x7fffu + ((u >> 16) & 1u)) >> 16);
}
// fast erf-gelu: Abramowitz-Stegun 7.1.26, |err_erf| < 1.5e-7
// R6: 1/x -> v_rcp (1 ulp; denominator in [1,inf) well-conditioned)
DEV float geluf(float x){
  float u  = x * 0.70710678118654752440f;
  float au = fabsf(u);
  float t  = __builtin_amdgcn_rcpf(fmaf(0.3275911f, au, 1.0f));
  float p  = t*(0.254829592f + t*(-0.284496736f + t*(1.421413741f +
             t*(-1.453152027f + t*1.061405429f))));
  float e  = __expf(-au*au);
  float E  = fmaf(-p, e, 1.0f);
  float er = copysignf(E, u);
  return 0.5f * x * (1.0f + er);
}

// ---------------------------------------------------------------------------
// Weight pre-pack: all weights as contiguous 32 KB N=128 panels in frag layout
//   dst[off + ((kk*128 + n)*4 + q)*8 + j] = src[(kk*32+q*8+j)*srcN + nbase + n]
// lw1 / headw (N=256 sources) are split into two column panels.
// ---------------------------------------------------------------------------
__global__ __launch_bounds__(256) void k_pack(
    const float* __restrict__ lw1, const float* __restrict__ lw2, const float* __restrict__ poolw,
    const float* __restrict__ mw1, const float* __restrict__ mw2, const float* __restrict__ uw1,
    const float* __restrict__ uw2, const float* __restrict__ bcw, const float* __restrict__ headw,
    u16* __restrict__ dst)
{
  int b = blockIdx.x;
  const float* src; int srcN, nbase = 0, off;
  if      (b < 64) {            src = lw1;  srcN = 256; nbase = 0;   off = 0;      }
  else if (b < 128){ b -= 64;   src = lw1;  srcN = 256; nbase = 128; off = 16384;  }
  else if (b < 256){ b -= 128;  src = lw2;  srcN = 128;              off = 32768;  }
  else if (b < 320){ b -= 256;  src = poolw;srcN = 128;              off = 65536;  }
  else if (b < 384){ b -= 320;  src = mw1;  srcN = 128;              off = 81920;  }
  else if (b < 448){ b -= 384;  src = mw1 + 16384; srcN = 128;       off = 98304;  }
  else if (b < 512){ b -= 448;  src = mw2;  srcN = 128;              off = 114688; }
  else if (b < 640){ b -= 512;  src = uw1;  srcN = 128;              off = 131072; }
  else if (b < 704){ b -= 640;  src = uw2;  srcN = 128;              off = 163840; }
  else if (b < 768){ b -= 704;  src = bcw;  srcN = 128;              off = 180224; }
  else if (b < 832){ b -= 768;  src = headw;srcN = 256; nbase = 0;   off = 196608; }
  else             { b -= 832;  src = headw;srcN = 256; nbase = 128; off = 212992; }
  int e = b * 256 + threadIdx.x;
  int j = e & 7, q = (e >> 3) & 3, rest = e >> 5;
  int n = rest & 127, kk = rest >> 7;
  int k = kk * 32 + q * 8 + j;
  dst[off + e] = f2b(src[k * srcN + nbase + n]);
}

// ---------------------------------------------------------------------------
// Shared MFMA helper: 16-row tile x 128 cols, K=128, B from an N=128 LDS panel
// ---------------------------------------------------------------------------
DEV void mma8(floatx4* acc, const u16* Arow, int ap, const u16* W, int l15, int q){
  const u16* ar = Arow + l15 * ap + q * 8;
#pragma unroll
  for (int kk = 0; kk < 4; kk++){
    bf16x8 av = *(const bf16x8*)(ar + kk * 32);
#pragma unroll
    for (int nt = 0; nt < 8; nt++){
      bf16x8 bv = *(const bf16x8*)(W + (size_t)((kk * 128 + nt * 16 + l15) * 4 + q) * 8);
      acc[nt] = __builtin_amdgcn_mfma_f32_16x16x32_bf16(av, bv, acc[nt], 0, 0, 0);
    }
  }
}

// 512-thread panel prefetch/commit: 32 KB = 2048 uint4, 4 per thread
#define PF512(P)  do{ const uint4* gs_ = (const uint4*)(P); \
                      pr0 = gs_[tid]; pr1 = gs_[tid + 512]; \
                      pr2 = gs_[tid + 1024]; pr3 = gs_[tid + 1536]; }while(0)
#define CM512(S)  do{ uint4* ss_ = (uint4*)(S); \
                      ss_[tid] = pr0; ss_[tid + 512] = pr1; \
                      ss_[tid + 1024] = pr2; ss_[tid + 1536] = pr3; }while(0)

// ---------------------------------------------------------------------------
// k_local v6: 1024 blocks x 512 threads (8 waves), 128 rows/block.
// h = emb[tok]+pos[c]; local = h + gelu(LN(h)@lw1+lb1)@lw2+lb2; + chunk means.
// Weight panels staged to LDS via double-buffered PF/CM (kills the per-wave
// same-address L2 weight stream that R5 counters implicate). Quad-shuffle LN.
// Panels in order: P0=lw1a, P1=lw2k0, P2=lw1b, P3=lw2k1.
// ---------------------------------------------------------------------------
__global__ __launch_bounds__(512, 1) void k_local(
    const int* __restrict__ x, const float* __restrict__ emb, const float* __restrict__ pos,
    const u16* __restrict__ lw1p, const float* __restrict__ lb1,
    const u16* __restrict__ lw2p, const float* __restrict__ lb2,
    const float* __restrict__ g, const float* __restrict__ bb,
    u16* __restrict__ outL, u16* __restrict__ summ)
{
  __shared__ __align__(16) u16 sA[128][136];
  __shared__ __align__(16) u16 sY[128][136];
  __shared__ __align__(16) u16 sW0[16384], sW1[16384];
  __shared__ int stok[128];
  const int tid = threadIdx.x;
  const int m0 = blockIdx.x * 128;
  uint4 pr0, pr1, pr2, pr3;
  PF512(lw1p);                                   // P0 = lw1 colsA
  if (tid < 128) stok[tid] = x[m0 + tid];
  const int r = tid >> 2, sg = tid & 3;
  // ---- phase A: h = emb + pos; quad-shuffle LN -> sA ----
  {
    const int tok = x[m0 + r];
    const float4* e4 = (const float4*)(emb + (size_t)tok * 128 + sg * 32);
    const float4* p4 = (const float4*)(pos + (r & 7) * 128 + sg * 32);
    float h[32];
    float s = 0.f, s2 = 0.f;
#pragma unroll
    for (int i = 0; i < 8; i++){
      float4 ev = e4[i], pv = p4[i];
      float v0 = ev.x + pv.x, v1 = ev.y + pv.y, v2 = ev.z + pv.z, v3 = ev.w + pv.w;
      h[i * 4 + 0] = v0; h[i * 4 + 1] = v1; h[i * 4 + 2] = v2; h[i * 4 + 3] = v3;
      s += v0 + v1 + v2 + v3;
      s2 += v0 * v0 + v1 * v1 + v2 * v2 + v3 * v3;
    }
    // row r = threads tid 4r..4r+3 -> 4 aligned consecutive lanes
    s  += __shfl_xor(s, 1, 64);   s  += __shfl_xor(s, 2, 64);
    s2 += __shfl_xor(s2, 1, 64);  s2 += __shfl_xor(s2, 2, 64);
    float mu = s * (1.f / 128.f);
    float rs = rsqrtf(s2 * (1.f / 128.f) - mu * mu + 1e-5f);
#pragma unroll
    for (int i = 0; i < 32; i++){
      int col = sg * 32 + i;
      sA[r][col] = f2b((h[i] - mu) * rs * g[col] + bb[col]);
    }
  }
  CM512(sW0);                                    // commit P0
  PF512(lw2p);                                   // P1 = lw2 k-half0
  __syncthreads();                               // B1: sA, sW0, stok ready

  const int lane = tid & 63, wv = tid >> 6, l15 = lane & 15, q = lane >> 4;
  // epilogue residuals issued early; consumed in phase 4 (latency hidden)
  float hre[8][4];
#pragma unroll
  for (int nt = 0; nt < 8; nt++){
    int col = nt * 16 + l15;
#pragma unroll
    for (int rr = 0; rr < 4; rr++){
      int row = wv * 16 + q * 4 + rr;
      hre[nt][rr] = emb[(size_t)stok[row] * 128 + col] + pos[(row & 7) * 128 + col];
    }
  }
  floatx4 a2[8];
#pragma unroll
  for (int i = 0; i < 8; i++) a2[i] = (floatx4)(0.0f);
  // ---- phase 1: GEMM1 colsA (sW0) -> gelu -> sY ----
  {
    floatx4 a1[8];
#pragma unroll
    for (int i = 0; i < 8; i++) a1[i] = (floatx4)(0.0f);
    mma8(a1, &sA[wv * 16][0], 136, sW0, l15, q);
    CM512(sW1);                                  // commit P1 (first sW1 use)
    PF512(lw1p + 16384);                         // P2 = lw1 colsB
#pragma unroll
    for (int nt = 0; nt < 8; nt++){
      int col = nt * 16 + l15;
      float bval = lb1[col];
#pragma unroll
      for (int rr = 0; rr < 4; rr++)
        sY[wv * 16 + q * 4 + rr][col] = f2b(geluf(a1[nt][rr] + bval));
    }
  }
  __syncthreads();                               // B2: sW1 + sY ready
  // ---- phase 2: GEMM2 k-half0 (sW1, sY) ----
  mma8(a2, &sY[wv * 16][0], 136, sW1, l15, q);
  CM512(sW0);                                    // commit P2 (sW0 readers done pre-B2)
  PF512(lw2p + 16384);                           // P3 = lw2 k-half1
  __syncthreads();                               // B3: sW0 ready; sY reads done
  // ---- phase 3: GEMM1 colsB (sW0) -> gelu -> sY (overwrite) ----
  {
    floatx4 a1[8];
#pragma unroll
    for (int i = 0; i < 8; i++) a1[i] = (floatx4)(0.0f);
    mma8(a1, &sA[wv * 16][0], 136, sW0, l15, q);
    CM512(sW1);                                  // commit P3 (sW1 readers done pre-B3)
#pragma unroll
    for (int nt = 0; nt < 8; nt++){
      int col = nt * 16 + l15;
      float bval = lb1[128 + col];
#pragma unroll
      for (int rr = 0; rr < 4; rr++)
        sY[wv * 16 + q * 4 + rr][col] = f2b(geluf(a1[nt][rr] + bval));
    }
  }
  __syncthreads();                               // B4: sW1 + sY ready
  // ---- phase 4: GEMM2 k-half1 (sW1, sY) + epilogue ----
  mma8(a2, &sY[wv * 16][0], 136, sW1, l15, q);
#pragma unroll
  for (int nt = 0; nt < 8; nt++){
    int col = nt * 16 + l15;
    float bval = lb2[col];
    float csum = 0.f;
#pragma unroll
    for (int rr = 0; rr < 4; rr++){
      int row = wv * 16 + q * 4 + rr;
      int gr = m0 + row;
      float v = a2[nt][rr] + bval + hre[nt][rr];
      outL[(size_t)gr * 128 + col] = f2b(v);
      csum += v;
    }
    csum += __shfl_xor(csum, 16, 64);            // q 0<->1, 2<->3: 8-row chunk sum
    if (!(q & 1)){
      int chunk = (m0 >> 3) + 2 * wv + (q >> 1);
      summ[(size_t)chunk * 128 + col] = f2b(csum * 0.125f);
    }
  }
}

// ---------------------------------------------------------------------------
// Fused message-passing (R3-proven, unchanged): pool GEMM + 3 rounds + bc.
// 256 blocks x 640 threads, double-buffered weight panels, reg prefetch.
// ---------------------------------------------------------------------------
DEV void mma_tile4(floatx4* acc, const u16* Arow, int ap, const u16* W,
                   int colbase, int l15, int q){
  const u16* ar = Arow + l15 * ap + q * 8;
#pragma unroll
  for (int kk = 0; kk < 4; kk++){
    bf16x8 av = *(const bf16x8*)(ar + kk * 32);
#pragma unroll
    for (int nt = 0; nt < 4; nt++){
      bf16x8 bv = *(const bf16x8*)(W + (size_t)((kk * 128 + colbase + nt * 16 + l15) * 4 + q) * 8);
      acc[nt] = __builtin_amdgcn_mfma_f32_16x16x32_bf16(av, bv, acc[nt], 0, 0, 0);
    }
  }
}

template<bool GELU>
DEV void store_tile4(const floatx4* acc, const float* bias, u16* Crow, int cp,
                     int colbase, int l15, int q){
#pragma unroll
  for (int nt = 0; nt < 4; nt++){
    int col = colbase + nt * 16 + l15;
    float bval = bias ? bias[col] : 0.f;
#pragma unroll
    for (int rr = 0; rr < 4; rr++){
      float v = acc[nt][rr] + bval;
      if (GELU) v = geluf(v);
      Crow[(q * 4 + rr) * cp + col] = f2b(v);
    }
  }
}

#define PF(P)    do{ const uint4* gs_ = (const uint4*)(P); \
                     pr0 = gs_[tid]; pr1 = gs_[tid + 640]; pr2 = gs_[tid + 1280]; \
                     if (tid < 128) pr3 = gs_[tid + 1920]; }while(0)
#define COMMIT(S) do{ uint4* ss_ = (uint4*)(S); \
                     ss_[tid] = pr0; ss_[tid + 640] = pr1; ss_[tid + 1280] = pr2; \
                     if (tid < 128) ss_[tid + 1920] = pr3; }while(0)

__global__ __launch_bounds__(640, 1) void k_rounds(
    const u16* __restrict__ summB,
    const u16* __restrict__ poolp, const float* __restrict__ poolb,
    const u16* __restrict__ mw1p, const float* __restrict__ mb1,
    const u16* __restrict__ mw2p, const float* __restrict__ mb2,
    const u16* __restrict__ uw1p, const float* __restrict__ ub1,
    const u16* __restrict__ uw2p, const float* __restrict__ ub2,
    const float* __restrict__ mlng, const float* __restrict__ mlnb,
    const u16* __restrict__ bcp, const float* __restrict__ bcb,
    u16* __restrict__ bcB)
{
  __shared__ __align__(16) u16 sH[80][136];   // hmsg
  __shared__ __align__(16) u16 sPQ[80][264];  // [P|Q]; reused: [agg | upd]
  __shared__ __align__(16) u16 sS[80][136];   // summ; msg means; t2
  __shared__ __align__(16) u16 sW0[16384];    // weight panel double-buffer
  __shared__ __align__(16) u16 sW1[16384];
  const int tid = threadIdx.x;
  const int m0 = blockIdx.x * 64;
  const int halo = (m0 & 1023) ? 12 : 0;
  const int lo = m0 - halo;
  uint4 pr0 = {0,0,0,0}, pr1 = {0,0,0,0}, pr2 = {0,0,0,0}, pr3 = {0,0,0,0};

  PF(poolp);
  // stage summ rows lo..lo+79 (clamped) into sS: 1280 uint4, 2 per thread
  {
#pragma unroll
    for (int k = 0; k < 2; k++){
      int idx = tid + k * 640;
      int rr = idx >> 4, c = idx & 15;
      int node = lo + rr; if (node > 16383) node = 16383;
      *(uint4*)&sS[rr][c * 8] = *(const uint4*)(summB + (size_t)node * 128 + c * 8);
    }
  }
  COMMIT(sW0);        // pool panel (waits its loads; once, at kernel start)
  PF(mw1p);           // P
  __syncthreads();

  const int lane = tid & 63, wv = tid >> 6, l15 = lane & 15, q = lane >> 4;
  const int rt = wv >> 1, ch = wv & 1, colbase = ch * 64;
  const int row0 = rt * 16;
  const int d0 = lane * 2;
  const float b1lo = mb1[d0],  b1hi = mb1[d0 + 1];
  const float glo  = mlng[d0], ghi  = mlng[d0 + 1];
  const float blo  = mlnb[d0], bhi  = mlnb[d0 + 1];

  // phase pool: hmsg = summ @ pool_w + pool_b
  {
    COMMIT(sW1);      // P (drained at last barrier -> no wait)
    PF(mw1p + 16384); // Q
    floatx4 acc[4];
#pragma unroll
    for (int i = 0; i < 4; i++) acc[i] = (floatx4)(0.0f);
    mma_tile4(acc, &sS[row0][0], 136, sW0, colbase, l15, q);
    store_tile4<false>(acc, poolb, &sH[row0][0], 136, colbase, l15, q);
  }
  __syncthreads();

  for (int rnd = 0; rnd < 3; rnd++){
    { // phase P: sPQ[:,0:128] = hmsg @ w1[0:128]
      COMMIT(sW0);    // Q
      PF(mw2p);
      floatx4 acc[4];
#pragma unroll
      for (int i = 0; i < 4; i++) acc[i] = (floatx4)(0.0f);
      mma_tile4(acc, &sH[row0][0], 136, sW1, colbase, l15, q);
      store_tile4<false>(acc, nullptr, &sPQ[row0][0], 264, colbase, l15, q);
    }
    __syncthreads();
    { // phase Q: sPQ[:,128:256] = hmsg @ w1[128:256]
      COMMIT(sW1);    // mw2
      PF(uw1p);       // uw1a
      floatx4 acc[4];
#pragma unroll
      for (int i = 0; i < 4; i++) acc[i] = (floatx4)(0.0f);
      mma_tile4(acc, &sH[row0][0], 136, sW0, colbase, l15, q);
      store_tile4<false>(acc, nullptr, &sPQ[row0][128], 264, colbase, l15, q);
    }
    __syncthreads();
    { // phase msg: s[r] = mean_d gelu(P[r] + Q[r-d] + b1), 8 rows/wave
      for (int it = 0; it < 8; it++){
        int rr = wv * 8 + it;
        int i = (lo + rr) & 1023;
        int nd = (i + 1 < 5) ? i + 1 : 5;
        int ndc = (nd < rr + 1) ? nd : rr + 1;   // clamp for garbage halo rows
        unsigned pv = *(const unsigned*)&sPQ[rr][d0];
        float p0 = lo2f(pv) + b1lo, p1 = hi2f(pv) + b1hi;
        float a0 = 0.f, a1 = 0.f;
        for (int d = 0; d < ndc; d++){
          unsigned qv = *(const unsigned*)&sPQ[rr - d][128 + d0];
          a0 += geluf(p0 + lo2f(qv));
          a1 += geluf(p1 + hi2f(qv));
        }
        float inv = 1.f / (float)nd;
        unsigned pack = (unsigned)f2b(a0 * inv) | (((unsigned)f2b(a1 * inv)) << 16);
        *(unsigned*)&sS[rr][d0] = pack;
      }
    }
    __syncthreads();
    { // phase agg: sPQ[:,0:128] = s @ mw2 + mb2
      COMMIT(sW0);    // uw1a
      PF(uw1p + 16384); // uw1b
      floatx4 acc[4];
#pragma unroll
      for (int i = 0; i < 4; i++) acc[i] = (floatx4)(0.0f);
      mma_tile4(acc, &sS[row0][0], 136, sW1, colbase, l15, q);
      store_tile4<false>(acc, mb2, &sPQ[row0][0], 264, colbase, l15, q);
    }
    __syncthreads();
    floatx4 acc2[4];
    { // phase t2a: acc2 = hmsg @ uw1[0:128]
      COMMIT(sW1);    // uw1b
      PF(uw2p);
#pragma unroll
      for (int i = 0; i < 4; i++) acc2[i] = (floatx4)(0.0f);
      mma_tile4(acc2, &sH[row0][0], 136, sW0, colbase, l15, q);
    }
    __syncthreads();
    { // phase t2b: acc2 += agg @ uw1[128:256]; sS = gelu(acc2 + ub1)
      COMMIT(sW0);    // uw2
      PF(rnd < 2 ? mw1p : bcp);
      mma_tile4(acc2, &sPQ[row0][0], 264, sW1, colbase, l15, q);
      store_tile4<true>(acc2, ub1, &sS[row0][0], 136, colbase, l15, q);
    }
    __syncthreads();
    { // phase upd: sPQ[:,128:256] = t2 @ uw2 + ub2
      COMMIT(sW1);    // next P or bc
      if (rnd < 2) PF(mw1p + 16384);   // next Q
      floatx4 acc[4];
#pragma unroll
      for (int i = 0; i < 4; i++) acc[i] = (floatx4)(0.0f);
      mma_tile4(acc, &sS[row0][0], 136, sW0, colbase, l15, q);
      store_tile4<false>(acc, ub2, &sPQ[row0][128], 264, colbase, l15, q);
    }
    __syncthreads();
    { // phase LN: hmsg = LN(hmsg + upd), 8 rows/wave
      for (int it = 0; it < 8; it++){
        int rr = wv * 8 + it;
        unsigned hv = *(const unsigned*)&sH[rr][d0];
        unsigned uv = *(const unsigned*)&sPQ[rr][128 + d0];
        float x0 = lo2f(hv) + lo2f(uv);
        float x1 = hi2f(hv) + hi2f(uv);
        float s = x0 + x1, s2 = x0 * x0 + x1 * x1;
#pragma unroll
        for (int off = 32; off; off >>= 1){
          s  += __shfl_xor(s, off, 64);
          s2 += __shfl_xor(s2, off, 64);
        }
        float mu = s * (1.f / 128.f);
        float rs = rsqrtf(s2 * (1.f / 128.f) - mu * mu + 1e-5f);
        float y0 = (x0 - mu) * rs * glo + blo;
        float y1 = (x1 - mu) * rs * ghi + bhi;
        unsigned pack = (unsigned)f2b(y0) | (((unsigned)f2b(y1)) << 16);
        *(unsigned*)&sH[rr][d0] = pack;
      }
    }
    __syncthreads();
  }
  { // final: bc = hmsg @ bc_w + bc_b, write owned rows only
    floatx4 acc[4];
#pragma unroll
    for (int i = 0; i < 4; i++) acc[i] = (floatx4)(0.0f);
    mma_tile4(acc, &sH[row0][0], 136, sW1, colbase, l15, q);
#pragma unroll
    for (int nt = 0; nt < 4; nt++){
      int col = colbase + nt * 16 + l15;
      float bval = bcb[col];
#pragma unroll
      for (int rr = 0; rr < 4; rr++){
        int row = row0 + q * 4 + rr;
        if (row >= halo && row < halo + 64){
          int node = lo + row;
          bcB[(size_t)node * 128 + col] = f2b(acc[nt][rr] + bval);
        }
      }
    }
  }
}

// ---------------------------------------------------------------------------
// k_head v6: 1024 blocks x 512 threads, 128 rows/block. LN(local+bc)@head_w.
// head panels (2 x 32 KB column halves) staged to LDS, double-buffered.
// ---------------------------------------------------------------------------
__global__ __launch_bounds__(512, 1) void k_head(
    const u16* __restrict__ localL, const u16* __restrict__ bcB,
    const float* __restrict__ g, const float* __restrict__ bb,
    const u16* __restrict__ headp, float* __restrict__ out)
{
  __shared__ __align__(16) u16 sA[128][136];
  __shared__ __align__(16) u16 sW0[16384], sW1[16384];
  const int tid = threadIdx.x;
  const int m0 = blockIdx.x * 128;
  uint4 pr0, pr1, pr2, pr3;
  PF512(headp);                                  // colsA
  const int r = tid >> 2, sg = tid & 3;
  // ---- phase A: quad-shuffle LN(local + bc) -> sA ----
  {
    const int gr = m0 + r;
    const uint4* l4 = (const uint4*)(localL + (size_t)gr * 128 + sg * 32);
    const uint4* c4 = (const uint4*)(bcB + (size_t)(gr >> 3) * 128 + sg * 32);
    float h[32];
    float s = 0.f, s2 = 0.f;
#pragma unroll
    for (int i = 0; i < 4; i++){
      uint4 lv = l4[i], cv = c4[i];
      unsigned lw[4] = {lv.x, lv.y, lv.z, lv.w}, cw[4] = {cv.x, cv.y, cv.z, cv.w};
#pragma unroll
      for (int j = 0; j < 4; j++){
        float v0 = lo2f(lw[j]) + lo2f(cw[j]);
        float v1 = hi2f(lw[j]) + hi2f(cw[j]);
        h[i * 8 + j * 2] = v0; h[i * 8 + j * 2 + 1] = v1;
        s += v0 + v1; s2 += v0 * v0 + v1 * v1;
      }
    }
    s  += __shfl_xor(s, 1, 64);   s  += __shfl_xor(s, 2, 64);
    s2 += __shfl_xor(s2, 1, 64);  s2 += __shfl_xor(s2, 2, 64);
    float mu = s * (1.f / 128.f);
    float rs = rsqrtf(s2 * (1.f / 128.f) - mu * mu + 1e-5f);
#pragma unroll
    for (int i = 0; i < 32; i++){
      int col = sg * 32 + i;
      sA[r][col] = f2b((h[i] - mu) * rs * g[col] + bb[col]);
    }
  }
  CM512(sW0);
  PF512(headp + 16384);                          // colsB
  __syncthreads();                               // B1
  const int lane = tid & 63, wv = tid >> 6, l15 = lane & 15, q = lane >> 4;
  { // N-half 0
    floatx4 acc[8];
#pragma unroll
    for (int i = 0; i < 8; i++) acc[i] = (floatx4)(0.0f);
    mma8(acc, &sA[wv * 16][0], 136, sW0, l15, q);
    CM512(sW1);                                  // first sW1 use is after B2
#pragma unroll
    for (int nt = 0; nt < 8; nt++){
      int col = nt * 16 + l15;
#pragma unroll
      for (int rr = 0; rr < 4; rr++){
        int row = wv * 16 + q * 4 + rr;
        out[(size_t)(m0 + row) * 256 + col] = acc[nt][rr];
      }
    }
  }
  __syncthreads();                               // B2
  { // N-half 1
    floatx4 acc[8];
#pragma unroll
    for (int i = 0; i < 8; i++) acc[i] = (floatx4)(0.0f);
    mma8(acc, &sA[wv * 16][0], 136, sW1, l15, q);
#pragma unroll
    for (int nt = 0; nt < 8; nt++){
      int col = 128 + nt * 16 + l15;
#pragma unroll
      for (int rr = 0; rr < 4; rr++){
        int row = wv * 16 + q * 4 + rr;
        out[(size_t)(m0 + row) * 256 + col] = acc[nt][rr];
      }
    }
  }
}

// ---------------------------------------------------------------------------

extern "C" void kernel_launch(void* const* d_in, const int* in_sizes, int n_in,
                              void* d_out, int out_size, void* d_ws, size_t ws_size,
                              hipStream_t stream)
{
  const int*   x     = (const int*)d_in[0];
  const float* emb   = (const float*)d_in[1];
  const float* pos   = (const float*)d_in[2];
  const float* lw1   = (const float*)d_in[3];
  const float* lb1   = (const float*)d_in[4];
  const float* lw2   = (const float*)d_in[5];
  const float* lb2   = (const float*)d_in[6];
  const float* llng  = (const float*)d_in[7];
  const float* llnb  = (const float*)d_in[8];
  const float* poolw = (const float*)d_in[9];
  const float* poolb = (const float*)d_in[10];
  const float* mw1   = (const float*)d_in[11];
  const float* mb1   = (const float*)d_in[12];
  const float* mw2   = (const float*)d_in[13];
  const float* mb2   = (const float*)d_in[14];
  const float* uw1   = (const float*)d_in[15];
  const float* ub1   = (const float*)d_in[16];
  const float* uw2   = (const float*)d_in[17];
  const float* ub2   = (const float*)d_in[18];
  const float* mlng  = (const float*)d_in[19];
  const float* mlnb  = (const float*)d_in[20];
  const float* bcw   = (const float*)d_in[21];
  const float* bcb   = (const float*)d_in[22];
  const float* flng  = (const float*)d_in[23];
  const float* flnb  = (const float*)d_in[24];
  const float* headw = (const float*)d_in[25];

  // ws layout: packed weight panels (448 KB) | localB bf16 | bcB bf16
  char* ws = (char*)d_ws;
  u16* wpack = (u16*)ws;
  u16* lw1p  = wpack;           // colsA; colsB at +16384
  u16* lw2p  = wpack + 32768;   // k-half0; k-half1 at +16384
  u16* poolp = wpack + 65536;
  u16* mw1p  = wpack + 81920;   // P panel; Q panel at +16384
  u16* mw2p  = wpack + 114688;
  u16* uw1p  = wpack + 131072;  // rows 0:128; rows 128:256 at +16384
  u16* uw2p  = wpack + 163840;
  u16* bcp   = wpack + 180224;
  u16* headp = wpack + 196608;  // colsA; colsB at +16384
  u16* localB = (u16*)(ws + 524288);       // 131072 x 128 bf16 = 33.55 MB
  u16* bcB    = (u16*)(ws + 34078720);     // 16384 x 128 bf16  = 4.19 MB

  // chunk means live in d_out (dead before k_head, which overwrites all of it)
  u16* summB = (u16*)d_out;                // 16384 x 128 bf16 = 4.19 MB

  k_pack<<<896, 256, 0, stream>>>(lw1, lw2, poolw, mw1, mw2, uw1, uw2, bcw, headw, wpack);
  k_local<<<1024, 512, 0, stream>>>(x, emb, pos, lw1p, lb1, lw2p, lb2, llng, llnb, localB, summB);
  k_rounds<<<256, 640, 0, stream>>>(summB, poolp, poolb, mw1p, mb1, mw2p, mb2,
                                    uw1p, ub1, uw2p, ub2, mlng, mlnb, bcp, bcb, bcB);
  k_head<<<1024, 512, 0, stream>>>(localB, bcB, flng, flnb, headp, (float*)d_out);
}

// Round 7
// 312.856 us; speedup vs baseline: 2.4130x; 1.3537x over previous
//
#include <hip/hip_runtime.h>

typedef unsigned short u16;
typedef __attribute__((ext_vector_type(8))) __bf16 bf16x8;
typedef __attribute__((ext_vector_type(4))) float floatx4;

#define DEV static __device__ __forceinline__

DEV float lo2f(unsigned v){ return __uint_as_float(v << 16); }
DEV float hi2f(unsigned v){ return __uint_as_float(v & 0xffff0000u); }
DEV u16 f2b(float f){
  unsigned u = __float_as_uint(f);
  return (u16)((u + 0x7fffu + ((u >> 16) & 1u)) >> 16);
}
// fast erf-gelu: Abramowitz-Stegun 7.1.26, |err_erf| < 1.5e-7
DEV float geluf(float x){
  float u  = x * 0.70710678118654752440f;
  float au = fabsf(u);
  float t  = __builtin_amdgcn_rcpf(fmaf(0.3275911f, au, 1.0f));
  float p  = t*(0.254829592f + t*(-0.284496736f + t*(1.421413741f +
             t*(-1.453152027f + t*1.061405429f))));
  float e  = __expf(-au*au);
  float E  = fmaf(-p, e, 1.0f);
  float er = copysignf(E, u);
  return 0.5f * x * (1.0f + er);
}

// ---------------------------------------------------------------------------
// Weight pre-pack (R6-proven): all weights as contiguous 32 KB N=128 panels
//   dst[off + ((kk*128 + n)*4 + q)*8 + j] = src[(kk*32+q*8+j)*srcN + nbase + n]
// lw1 / headw (N=256 sources) split into two column panels.
// ---------------------------------------------------------------------------
__global__ __launch_bounds__(256) void k_pack(
    const float* __restrict__ lw1, const float* __restrict__ lw2, const float* __restrict__ poolw,
    const float* __restrict__ mw1, const float* __restrict__ mw2, const float* __restrict__ uw1,
    const float* __restrict__ uw2, const float* __restrict__ bcw, const float* __restrict__ headw,
    u16* __restrict__ dst)
{
  int b = blockIdx.x;
  const float* src; int srcN, nbase = 0, off;
  if      (b < 64) {            src = lw1;  srcN = 256; nbase = 0;   off = 0;      }
  else if (b < 128){ b -= 64;   src = lw1;  srcN = 256; nbase = 128; off = 16384;  }
  else if (b < 256){ b -= 128;  src = lw2;  srcN = 128;              off = 32768;  }
  else if (b < 320){ b -= 256;  src = poolw;srcN = 128;              off = 65536;  }
  else if (b < 384){ b -= 320;  src = mw1;  srcN = 128;              off = 81920;  }
  else if (b < 448){ b -= 384;  src = mw1 + 16384; srcN = 128;       off = 98304;  }
  else if (b < 512){ b -= 448;  src = mw2;  srcN = 128;              off = 114688; }
  else if (b < 640){ b -= 512;  src = uw1;  srcN = 128;              off = 131072; }
  else if (b < 704){ b -= 640;  src = uw2;  srcN = 128;              off = 163840; }
  else if (b < 768){ b -= 704;  src = bcw;  srcN = 128;              off = 180224; }
  else if (b < 832){ b -= 768;  src = headw;srcN = 256; nbase = 0;   off = 196608; }
  else             { b -= 832;  src = headw;srcN = 256; nbase = 128; off = 212992; }
  int e = b * 256 + threadIdx.x;
  int j = e & 7, q = (e >> 3) & 3, rest = e >> 5;
  int n = rest & 127, kk = rest >> 7;
  int k = kk * 32 + q * 8 + j;
  dst[off + e] = f2b(src[k * srcN + nbase + n]);
}

// ---------------------------------------------------------------------------
// Shared MFMA helper: 16-row tile x 128 cols, K=128, B = N=128 panel (LDS or
// global; fragment layout identical).
// ---------------------------------------------------------------------------
DEV void mma8(floatx4* acc, const u16* Arow, int ap, const u16* W, int l15, int q){
  const u16* ar = Arow + l15 * ap + q * 8;
#pragma unroll
  for (int kk = 0; kk < 4; kk++){
    bf16x8 av = *(const bf16x8*)(ar + kk * 32);
#pragma unroll
    for (int nt = 0; nt < 8; nt++){
      bf16x8 bv = *(const bf16x8*)(W + (size_t)((kk * 128 + nt * 16 + l15) * 4 + q) * 8);
      acc[nt] = __builtin_amdgcn_mfma_f32_16x16x32_bf16(av, bv, acc[nt], 0, 0, 0);
    }
  }
}

// ---------------------------------------------------------------------------
// k_table: table[tok*8+c] = local row for (tok,c). 2048 rows total.
// 32 blocks x 256 threads (4 waves), 64 rows/block. R6's proven 4-phase GEMM
// (lw1 colsA/colsB, lw2 khalf0/khalf1); weights read from global (L2-hot at
// 32 blocks). Quad-shuffle LN.
// ---------------------------------------------------------------------------
__global__ __launch_bounds__(256) void k_table(
    const float* __restrict__ emb, const float* __restrict__ pos,
    const u16* __restrict__ lw1p, const float* __restrict__ lb1,
    const u16* __restrict__ lw2p, const float* __restrict__ lb2,
    const float* __restrict__ g, const float* __restrict__ bb,
    u16* __restrict__ table)
{
  __shared__ __align__(16) u16 sA[64][136];
  __shared__ __align__(16) u16 sY[64][136];
  const int tid = threadIdx.x;
  const int m0 = blockIdx.x * 64;
  const int r = tid >> 2, sg = tid & 3;
  // ---- phase A: h = emb[tok] + pos[c]; quad-shuffle LN -> sA ----
  {
    const int row = m0 + r, tok = row >> 3, c = row & 7;
    const float4* e4 = (const float4*)(emb + (size_t)tok * 128 + sg * 32);
    const float4* p4 = (const float4*)(pos + c * 128 + sg * 32);
    float h[32];
    float s = 0.f, s2 = 0.f;
#pragma unroll
    for (int i = 0; i < 8; i++){
      float4 ev = e4[i], pv = p4[i];
      float v0 = ev.x + pv.x, v1 = ev.y + pv.y, v2 = ev.z + pv.z, v3 = ev.w + pv.w;
      h[i * 4 + 0] = v0; h[i * 4 + 1] = v1; h[i * 4 + 2] = v2; h[i * 4 + 3] = v3;
      s += v0 + v1 + v2 + v3;
      s2 += v0 * v0 + v1 * v1 + v2 * v2 + v3 * v3;
    }
    s  += __shfl_xor(s, 1, 64);   s  += __shfl_xor(s, 2, 64);
    s2 += __shfl_xor(s2, 1, 64);  s2 += __shfl_xor(s2, 2, 64);
    float mu = s * (1.f / 128.f);
    float rs = rsqrtf(s2 * (1.f / 128.f) - mu * mu + 1e-5f);
#pragma unroll
    for (int i = 0; i < 32; i++){
      int col = sg * 32 + i;
      sA[r][col] = f2b((h[i] - mu) * rs * g[col] + bb[col]);
    }
  }
  __syncthreads();
  const int lane = tid & 63, wv = tid >> 6, l15 = lane & 15, q = lane >> 4;
  floatx4 a2[8];
#pragma unroll
  for (int i = 0; i < 8; i++) a2[i] = (floatx4)(0.0f);
  // phase 1: GEMM1 colsA -> gelu -> sY
  {
    floatx4 a1[8];
#pragma unroll
    for (int i = 0; i < 8; i++) a1[i] = (floatx4)(0.0f);
    mma8(a1, &sA[wv * 16][0], 136, lw1p, l15, q);
#pragma unroll
    for (int nt = 0; nt < 8; nt++){
      int col = nt * 16 + l15;
      float bval = lb1[col];
#pragma unroll
      for (int rr = 0; rr < 4; rr++)
        sY[wv * 16 + q * 4 + rr][col] = f2b(geluf(a1[nt][rr] + bval));
    }
  }
  __syncthreads();
  // phase 2: GEMM2 k-half0
  mma8(a2, &sY[wv * 16][0], 136, lw2p, l15, q);
  __syncthreads();       // sY reads done before overwrite
  // phase 3: GEMM1 colsB -> gelu -> sY
  {
    floatx4 a1[8];
#pragma unroll
    for (int i = 0; i < 8; i++) a1[i] = (floatx4)(0.0f);
    mma8(a1, &sA[wv * 16][0], 136, lw1p + 16384, l15, q);
#pragma unroll
    for (int nt = 0; nt < 8; nt++){
      int col = nt * 16 + l15;
      float bval = lb1[128 + col];
#pragma unroll
      for (int rr = 0; rr < 4; rr++)
        sY[wv * 16 + q * 4 + rr][col] = f2b(geluf(a1[nt][rr] + bval));
    }
  }
  __syncthreads();
  // phase 4: GEMM2 k-half1 + epilogue residual + store
  mma8(a2, &sY[wv * 16][0], 136, lw2p + 16384, l15, q);
#pragma unroll
  for (int nt = 0; nt < 8; nt++){
    int col = nt * 16 + l15;
    float bval = lb2[col];
#pragma unroll
    for (int rr = 0; rr < 4; rr++){
      int row = wv * 16 + q * 4 + rr;
      int gr = m0 + row, tok = gr >> 3, c = gr & 7;
      float hres = emb[(size_t)tok * 128 + col] + pos[c * 128 + col];
      table[(size_t)gr * 128 + col] = f2b(a2[nt][rr] + bval + hres);
    }
  }
}

// ---------------------------------------------------------------------------
// k_summ: summ[ch] = (1/8) sum_j table[x[ch*8+j]*8 + j]. 256 blocks x 256 thr,
// 64 chunks/block, 4 threads/chunk (32 cols each). Table is L2-resident.
// ---------------------------------------------------------------------------
__global__ __launch_bounds__(256) void k_summ(
    const int* __restrict__ x, const u16* __restrict__ table, u16* __restrict__ summ)
{
  __shared__ int stok[512];
  const int tid = threadIdx.x;
  const int ch0 = blockIdx.x * 64;
  stok[tid] = x[ch0 * 8 + tid];
  stok[tid + 256] = x[ch0 * 8 + 256 + tid];
  __syncthreads();
  const int lc = tid >> 2, sg = tid & 3;
  float acc[32];
#pragma unroll
  for (int i = 0; i < 32; i++) acc[i] = 0.f;
#pragma unroll
  for (int j = 0; j < 8; j++){
    int row = stok[lc * 8 + j] * 8 + j;
    const uint4* t4 = (const uint4*)(table + (size_t)row * 128 + sg * 32);
#pragma unroll
    for (int i = 0; i < 4; i++){
      uint4 v = t4[i];
      unsigned w[4] = {v.x, v.y, v.z, v.w};
#pragma unroll
      for (int k = 0; k < 4; k++){
        acc[i * 8 + k * 2]     += lo2f(w[k]);
        acc[i * 8 + k * 2 + 1] += hi2f(w[k]);
      }
    }
  }
  unsigned* dst = (unsigned*)(summ + (size_t)(ch0 + lc) * 128 + sg * 32);
#pragma unroll
  for (int i = 0; i < 16; i++)
    dst[i] = (unsigned)f2b(acc[2 * i] * 0.125f) | (((unsigned)f2b(acc[2 * i + 1] * 0.125f)) << 16);
}

// ---------------------------------------------------------------------------
// Fused message-passing (R3-proven, unchanged): pool GEMM + 3 rounds + bc.
// 256 blocks x 640 threads, double-buffered weight panels, reg prefetch.
// ---------------------------------------------------------------------------
DEV void mma_tile4(floatx4* acc, const u16* Arow, int ap, const u16* W,
                   int colbase, int l15, int q){
  const u16* ar = Arow + l15 * ap + q * 8;
#pragma unroll
  for (int kk = 0; kk < 4; kk++){
    bf16x8 av = *(const bf16x8*)(ar + kk * 32);
#pragma unroll
    for (int nt = 0; nt < 4; nt++){
      bf16x8 bv = *(const bf16x8*)(W + (size_t)((kk * 128 + colbase + nt * 16 + l15) * 4 + q) * 8);
      acc[nt] = __builtin_amdgcn_mfma_f32_16x16x32_bf16(av, bv, acc[nt], 0, 0, 0);
    }
  }
}

template<bool GELU>
DEV void store_tile4(const floatx4* acc, const float* bias, u16* Crow, int cp,
                     int colbase, int l15, int q){
#pragma unroll
  for (int nt = 0; nt < 4; nt++){
    int col = colbase + nt * 16 + l15;
    float bval = bias ? bias[col] : 0.f;
#pragma unroll
    for (int rr = 0; rr < 4; rr++){
      float v = acc[nt][rr] + bval;
      if (GELU) v = geluf(v);
      Crow[(q * 4 + rr) * cp + col] = f2b(v);
    }
  }
}

#define PF(P)    do{ const uint4* gs_ = (const uint4*)(P); \
                     pr0 = gs_[tid]; pr1 = gs_[tid + 640]; pr2 = gs_[tid + 1280]; \
                     if (tid < 128) pr3 = gs_[tid + 1920]; }while(0)
#define COMMIT(S) do{ uint4* ss_ = (uint4*)(S); \
                     ss_[tid] = pr0; ss_[tid + 640] = pr1; ss_[tid + 1280] = pr2; \
                     if (tid < 128) ss_[tid + 1920] = pr3; }while(0)

__global__ __launch_bounds__(640, 1) void k_rounds(
    const u16* __restrict__ summB,
    const u16* __restrict__ poolp, const float* __restrict__ poolb,
    const u16* __restrict__ mw1p, const float* __restrict__ mb1,
    const u16* __restrict__ mw2p, const float* __restrict__ mb2,
    const u16* __restrict__ uw1p, const float* __restrict__ ub1,
    const u16* __restrict__ uw2p, const float* __restrict__ ub2,
    const float* __restrict__ mlng, const float* __restrict__ mlnb,
    const u16* __restrict__ bcp, const float* __restrict__ bcb,
    u16* __restrict__ bcB)
{
  __shared__ __align__(16) u16 sH[80][136];   // hmsg
  __shared__ __align__(16) u16 sPQ[80][264];  // [P|Q]; reused: [agg | upd]
  __shared__ __align__(16) u16 sS[80][136];   // summ; msg means; t2
  __shared__ __align__(16) u16 sW0[16384];    // weight panel double-buffer
  __shared__ __align__(16) u16 sW1[16384];
  const int tid = threadIdx.x;
  const int m0 = blockIdx.x * 64;
  const int halo = (m0 & 1023) ? 12 : 0;
  const int lo = m0 - halo;
  uint4 pr0 = {0,0,0,0}, pr1 = {0,0,0,0}, pr2 = {0,0,0,0}, pr3 = {0,0,0,0};

  PF(poolp);
  // stage summ rows lo..lo+79 (clamped) into sS: 1280 uint4, 2 per thread
  {
#pragma unroll
    for (int k = 0; k < 2; k++){
      int idx = tid + k * 640;
      int rr = idx >> 4, c = idx & 15;
      int node = lo + rr; if (node > 16383) node = 16383;
      *(uint4*)&sS[rr][c * 8] = *(const uint4*)(summB + (size_t)node * 128 + c * 8);
    }
  }
  COMMIT(sW0);        // pool panel (waits its loads; once, at kernel start)
  PF(mw1p);           // P
  __syncthreads();

  const int lane = tid & 63, wv = tid >> 6, l15 = lane & 15, q = lane >> 4;
  const int rt = wv >> 1, ch = wv & 1, colbase = ch * 64;
  const int row0 = rt * 16;
  const int d0 = lane * 2;
  const float b1lo = mb1[d0],  b1hi = mb1[d0 + 1];
  const float glo  = mlng[d0], ghi  = mlng[d0 + 1];
  const float blo  = mlnb[d0], bhi  = mlnb[d0 + 1];

  // phase pool: hmsg = summ @ pool_w + pool_b
  {
    COMMIT(sW1);      // P (drained at last barrier -> no wait)
    PF(mw1p + 16384); // Q
    floatx4 acc[4];
#pragma unroll
    for (int i = 0; i < 4; i++) acc[i] = (floatx4)(0.0f);
    mma_tile4(acc, &sS[row0][0], 136, sW0, colbase, l15, q);
    store_tile4<false>(acc, poolb, &sH[row0][0], 136, colbase, l15, q);
  }
  __syncthreads();

  for (int rnd = 0; rnd < 3; rnd++){
    { // phase P: sPQ[:,0:128] = hmsg @ w1[0:128]
      COMMIT(sW0);    // Q
      PF(mw2p);
      floatx4 acc[4];
#pragma unroll
      for (int i = 0; i < 4; i++) acc[i] = (floatx4)(0.0f);
      mma_tile4(acc, &sH[row0][0], 136, sW1, colbase, l15, q);
      store_tile4<false>(acc, nullptr, &sPQ[row0][0], 264, colbase, l15, q);
    }
    __syncthreads();
    { // phase Q: sPQ[:,128:256] = hmsg @ w1[128:256]
      COMMIT(sW1);    // mw2
      PF(uw1p);       // uw1a
      floatx4 acc[4];
#pragma unroll
      for (int i = 0; i < 4; i++) acc[i] = (floatx4)(0.0f);
      mma_tile4(acc, &sH[row0][0], 136, sW0, colbase, l15, q);
      store_tile4<false>(acc, nullptr, &sPQ[row0][128], 264, colbase, l15, q);
    }
    __syncthreads();
    { // phase msg: s[r] = mean_d gelu(P[r] + Q[r-d] + b1), 8 rows/wave
      for (int it = 0; it < 8; it++){
        int rr = wv * 8 + it;
        int i = (lo + rr) & 1023;
        int nd = (i + 1 < 5) ? i + 1 : 5;
        int ndc = (nd < rr + 1) ? nd : rr + 1;   // clamp for garbage halo rows
        unsigned pv = *(const unsigned*)&sPQ[rr][d0];
        float p0 = lo2f(pv) + b1lo, p1 = hi2f(pv) + b1hi;
        float a0 = 0.f, a1 = 0.f;
        for (int d = 0; d < ndc; d++){
          unsigned qv = *(const unsigned*)&sPQ[rr - d][128 + d0];
          a0 += geluf(p0 + lo2f(qv));
          a1 += geluf(p1 + hi2f(qv));
        }
        float inv = 1.f / (float)nd;
        unsigned pack = (unsigned)f2b(a0 * inv) | (((unsigned)f2b(a1 * inv)) << 16);
        *(unsigned*)&sS[rr][d0] = pack;
      }
    }
    __syncthreads();
    { // phase agg: sPQ[:,0:128] = s @ mw2 + mb2
      COMMIT(sW0);    // uw1a
      PF(uw1p + 16384); // uw1b
      floatx4 acc[4];
#pragma unroll
      for (int i = 0; i < 4; i++) acc[i] = (floatx4)(0.0f);
      mma_tile4(acc, &sS[row0][0], 136, sW1, colbase, l15, q);
      store_tile4<false>(acc, mb2, &sPQ[row0][0], 264, colbase, l15, q);
    }
    __syncthreads();
    floatx4 acc2[4];
    { // phase t2a: acc2 = hmsg @ uw1[0:128]
      COMMIT(sW1);    // uw1b
      PF(uw2p);
#pragma unroll
      for (int i = 0; i < 4; i++) acc2[i] = (floatx4)(0.0f);
      mma_tile4(acc2, &sH[row0][0], 136, sW0, colbase, l15, q);
    }
    __syncthreads();
    { // phase t2b: acc2 += agg @ uw1[128:256]; sS = gelu(acc2 + ub1)
      COMMIT(sW0);    // uw2
      PF(rnd < 2 ? mw1p : bcp);
      mma_tile4(acc2, &sPQ[row0][0], 264, sW1, colbase, l15, q);
      store_tile4<true>(acc2, ub1, &sS[row0][0], 136, colbase, l15, q);
    }
    __syncthreads();
    { // phase upd: sPQ[:,128:256] = t2 @ uw2 + ub2
      COMMIT(sW1);    // next P or bc
      if (rnd < 2) PF(mw1p + 16384);   // next Q
      floatx4 acc[4];
#pragma unroll
      for (int i = 0; i < 4; i++) acc[i] = (floatx4)(0.0f);
      mma_tile4(acc, &sS[row0][0], 136, sW0, colbase, l15, q);
      store_tile4<false>(acc, ub2, &sPQ[row0][128], 264, colbase, l15, q);
    }
    __syncthreads();
    { // phase LN: hmsg = LN(hmsg + upd), 8 rows/wave
      for (int it = 0; it < 8; it++){
        int rr = wv * 8 + it;
        unsigned hv = *(const unsigned*)&sH[rr][d0];
        unsigned uv = *(const unsigned*)&sPQ[rr][128 + d0];
        float x0 = lo2f(hv) + lo2f(uv);
        float x1 = hi2f(hv) + hi2f(uv);
        float s = x0 + x1, s2 = x0 * x0 + x1 * x1;
#pragma unroll
        for (int off = 32; off; off >>= 1){
          s  += __shfl_xor(s, off, 64);
          s2 += __shfl_xor(s2, off, 64);
        }
        float mu = s * (1.f / 128.f);
        float rs = rsqrtf(s2 * (1.f / 128.f) - mu * mu + 1e-5f);
        float y0 = (x0 - mu) * rs * glo + blo;
        float y1 = (x1 - mu) * rs * ghi + bhi;
        unsigned pack = (unsigned)f2b(y0) | (((unsigned)f2b(y1)) << 16);
        *(unsigned*)&sH[rr][d0] = pack;
      }
    }
    __syncthreads();
  }
  { // final: bc = hmsg @ bc_w + bc_b, write owned rows only
    floatx4 acc[4];
#pragma unroll
    for (int i = 0; i < 4; i++) acc[i] = (floatx4)(0.0f);
    mma_tile4(acc, &sH[row0][0], 136, sW1, colbase, l15, q);
#pragma unroll
    for (int nt = 0; nt < 4; nt++){
      int col = colbase + nt * 16 + l15;
      float bval = bcb[col];
#pragma unroll
      for (int rr = 0; rr < 4; rr++){
        int row = row0 + q * 4 + rr;
        if (row >= halo && row < halo + 64){
          int node = lo + row;
          bcB[(size_t)node * 128 + col] = f2b(acc[nt][rr] + bval);
        }
      }
    }
  }
}

// 512-thread panel prefetch/commit: 32 KB = 2048 uint4, 4 per thread
#define PF512(P)  do{ const uint4* gs_ = (const uint4*)(P); \
                      pr0 = gs_[tid]; pr1 = gs_[tid + 512]; \
                      pr2 = gs_[tid + 1024]; pr3 = gs_[tid + 1536]; }while(0)
#define CM512(S)  do{ uint4* ss_ = (uint4*)(S); \
                      ss_[tid] = pr0; ss_[tid + 512] = pr1; \
                      ss_[tid + 1024] = pr2; ss_[tid + 1536] = pr3; }while(0)

// ---------------------------------------------------------------------------
// k_head v7 (R6-proven structure; localL read replaced by table gather):
// out = LN(table[x[gr]*8+(gr&7)] + bc[gr>>3]) @ head_w. 1024 blocks x 512 thr.
// ---------------------------------------------------------------------------
__global__ __launch_bounds__(512, 1) void k_head(
    const int* __restrict__ x, const u16* __restrict__ table,
    const u16* __restrict__ bcB,
    const float* __restrict__ g, const float* __restrict__ bb,
    const u16* __restrict__ headp, float* __restrict__ out)
{
  __shared__ __align__(16) u16 sA[128][136];
  __shared__ __align__(16) u16 sW0[16384], sW1[16384];
  const int tid = threadIdx.x;
  const int m0 = blockIdx.x * 128;
  uint4 pr0, pr1, pr2, pr3;
  PF512(headp);                                  // colsA
  const int r = tid >> 2, sg = tid & 3;
  // ---- phase A: quad-shuffle LN(local + bc) -> sA ----
  {
    const int gr = m0 + r;
    const int trow = x[gr] * 8 + (gr & 7);
    const uint4* l4 = (const uint4*)(table + (size_t)trow * 128 + sg * 32);
    const uint4* c4 = (const uint4*)(bcB + (size_t)(gr >> 3) * 128 + sg * 32);
    float h[32];
    float s = 0.f, s2 = 0.f;
#pragma unroll
    for (int i = 0; i < 4; i++){
      uint4 lv = l4[i], cv = c4[i];
      unsigned lw[4] = {lv.x, lv.y, lv.z, lv.w}, cw[4] = {cv.x, cv.y, cv.z, cv.w};
#pragma unroll
      for (int j = 0; j < 4; j++){
        float v0 = lo2f(lw[j]) + lo2f(cw[j]);
        float v1 = hi2f(lw[j]) + hi2f(cw[j]);
        h[i * 8 + j * 2] = v0; h[i * 8 + j * 2 + 1] = v1;
        s += v0 + v1; s2 += v0 * v0 + v1 * v1;
      }
    }
    s  += __shfl_xor(s, 1, 64);   s  += __shfl_xor(s, 2, 64);
    s2 += __shfl_xor(s2, 1, 64);  s2 += __shfl_xor(s2, 2, 64);
    float mu = s * (1.f / 128.f);
    float rs = rsqrtf(s2 * (1.f / 128.f) - mu * mu + 1e-5f);
#pragma unroll
    for (int i = 0; i < 32; i++){
      int col = sg * 32 + i;
      sA[r][col] = f2b((h[i] - mu) * rs * g[col] + bb[col]);
    }
  }
  CM512(sW0);
  PF512(headp + 16384);                          // colsB
  __syncthreads();                               // B1
  const int lane = tid & 63, wv = tid >> 6, l15 = lane & 15, q = lane >> 4;
  { // N-half 0
    floatx4 acc[8];
#pragma unroll
    for (int i = 0; i < 8; i++) acc[i] = (floatx4)(0.0f);
    mma8(acc, &sA[wv * 16][0], 136, sW0, l15, q);
    CM512(sW1);                                  // first sW1 use is after B2
#pragma unroll
    for (int nt = 0; nt < 8; nt++){
      int col = nt * 16 + l15;
#pragma unroll
      for (int rr = 0; rr < 4; rr++){
        int row = wv * 16 + q * 4 + rr;
        out[(size_t)(m0 + row) * 256 + col] = acc[nt][rr];
      }
    }
  }
  __syncthreads();                               // B2
  { // N-half 1
    floatx4 acc[8];
#pragma unroll
    for (int i = 0; i < 8; i++) acc[i] = (floatx4)(0.0f);
    mma8(acc, &sA[wv * 16][0], 136, sW1, l15, q);
#pragma unroll
    for (int nt = 0; nt < 8; nt++){
      int col = 128 + nt * 16 + l15;
#pragma unroll
      for (int rr = 0; rr < 4; rr++){
        int row = wv * 16 + q * 4 + rr;
        out[(size_t)(m0 + row) * 256 + col] = acc[nt][rr];
      }
    }
  }
}

// ---------------------------------------------------------------------------

extern "C" void kernel_launch(void* const* d_in, const int* in_sizes, int n_in,
                              void* d_out, int out_size, void* d_ws, size_t ws_size,
                              hipStream_t stream)
{
  const int*   x     = (const int*)d_in[0];
  const float* emb   = (const float*)d_in[1];
  const float* pos   = (const float*)d_in[2];
  const float* lw1   = (const float*)d_in[3];
  const float* lb1   = (const float*)d_in[4];
  const float* lw2   = (const float*)d_in[5];
  const float* lb2   = (const float*)d_in[6];
  const float* llng  = (const float*)d_in[7];
  const float* llnb  = (const float*)d_in[8];
  const float* poolw = (const float*)d_in[9];
  const float* poolb = (const float*)d_in[10];
  const float* mw1   = (const float*)d_in[11];
  const float* mb1   = (const float*)d_in[12];
  const float* mw2   = (const float*)d_in[13];
  const float* mb2   = (const float*)d_in[14];
  const float* uw1   = (const float*)d_in[15];
  const float* ub1   = (const float*)d_in[16];
  const float* uw2   = (const float*)d_in[17];
  const float* ub2   = (const float*)d_in[18];
  const float* mlng  = (const float*)d_in[19];
  const float* mlnb  = (const float*)d_in[20];
  const float* bcw   = (const float*)d_in[21];
  const float* bcb   = (const float*)d_in[22];
  const float* flng  = (const float*)d_in[23];
  const float* flnb  = (const float*)d_in[24];
  const float* headw = (const float*)d_in[25];

  // ws layout (~9.4 MB): packed panels | table | summB | bcB
  char* ws = (char*)d_ws;
  u16* wpack = (u16*)ws;
  u16* lw1p  = wpack;           // colsA; colsB at +16384
  u16* lw2p  = wpack + 32768;   // k-half0; k-half1 at +16384
  u16* poolp = wpack + 65536;
  u16* mw1p  = wpack + 81920;   // P panel; Q panel at +16384
  u16* mw2p  = wpack + 114688;
  u16* uw1p  = wpack + 131072;  // rows 0:128; rows 128:256 at +16384
  u16* uw2p  = wpack + 163840;
  u16* bcp   = wpack + 180224;
  u16* headp = wpack + 196608;  // colsA; colsB at +16384
  u16* table = (u16*)(ws + 524288);        // 2048 x 128 bf16 = 512 KB
  u16* summB = (u16*)(ws + 1048576);       // 16384 x 128 bf16 = 4.19 MB
  u16* bcB   = (u16*)(ws + 5242880);       // 16384 x 128 bf16 = 4.19 MB

  k_pack<<<896, 256, 0, stream>>>(lw1, lw2, poolw, mw1, mw2, uw1, uw2, bcw, headw, wpack);
  k_table<<<32, 256, 0, stream>>>(emb, pos, lw1p, lb1, lw2p, lb2, llng, llnb, table);
  k_summ<<<256, 256, 0, stream>>>(x, table, summB);
  k_rounds<<<256, 640, 0, stream>>>(summB, poolp, poolb, mw1p, mb1, mw2p, mb2,
                                    uw1p, ub1, uw2p, ub2, mlng, mlnb, bcp, bcb, bcB);
  k_head<<<1024, 512, 0, stream>>>(x, table, bcB, flng, flnb, headp, (float*)d_out);
}